// Round 3
// baseline (495.204 us; speedup 1.0000x reference)
//
#include <hip/hip_runtime.h>
#include <hip/hip_bf16.h>

#define T_SEQ 2048
#define E_DIM 1024
#define HSZ   64
#define NBAT  4

// ---------------------------------------------------------------------------
// Kernel 1: Wpr[j][f] = sum_{h=0..15} Wp[h*64+j][f]   (64 x 1024)
// The reference tiles one head 16x then projects; tiling folds into Wp rows.
// ---------------------------------------------------------------------------
__global__ __launch_bounds__(256) void wpr_kernel(const float* __restrict__ Wp,
                                                  float* __restrict__ Wpr) {
  int idx = blockIdx.x * 256 + threadIdx.x;   // 0..65535
  int f = idx & (E_DIM - 1);
  int j = idx >> 10;                          // 0..63
  float s = 0.f;
#pragma unroll
  for (int h = 0; h < 16; ++h) s += Wp[(size_t)(h * HSZ + j) * E_DIM + f];
  Wpr[idx] = s;
}

// ---------------------------------------------------------------------------
// Kernel 2: Q/K/V = X @ W   ([8192 x 1024] @ [1024 x 64])
// blockIdx.y selects Wq/Wk/Wv. 64x64 output tile, BK=32, 4x4 reg tiles.
// ---------------------------------------------------------------------------
__global__ __launch_bounds__(256) void qkv_kernel(const float* __restrict__ X,
    const float* __restrict__ Wq, const float* __restrict__ Wk,
    const float* __restrict__ Wv,
    float* __restrict__ Qo, float* __restrict__ Ko, float* __restrict__ Vo) {
  const float* W; float* O;
  if (blockIdx.y == 0)      { W = Wq; O = Qo; }
  else if (blockIdx.y == 1) { W = Wk; O = Ko; }
  else                      { W = Wv; O = Vo; }

  __shared__ float Xs[32][68];   // [k][m], stride 68 floats = 272B (16B aligned)
  __shared__ float Ws[32][68];   // [k][n]

  const int tid = threadIdx.x;
  const int tx = tid & 15, ty = tid >> 4;
  const int row0 = blockIdx.x * 64;

  float acc[4][4] = {};

  for (int k0 = 0; k0 < E_DIM; k0 += 32) {
    {   // stage X^T tile (rows row0..+63, cols k0..+31)
      int c = tid & 31, r0 = tid >> 5;  // c: k-local, r0: 0..7
#pragma unroll
      for (int it = 0; it < 8; ++it) {
        int r = r0 + it * 8;
        Xs[c][r] = X[(size_t)(row0 + r) * E_DIM + k0 + c];
      }
    }
    {   // stage W tile (rows k0..+31, cols 0..63)
      int c = tid & 63, r0 = tid >> 6;  // r0: 0..3
#pragma unroll
      for (int it = 0; it < 8; ++it) {
        int r = r0 + it * 4;
        Ws[r][c] = W[(size_t)(k0 + r) * HSZ + c];
      }
    }
    __syncthreads();
#pragma unroll
    for (int kk = 0; kk < 32; ++kk) {
      float4 a = *(const float4*)&Xs[kk][ty * 4];
      float4 b = *(const float4*)&Ws[kk][tx * 4];
      float av[4] = {a.x, a.y, a.z, a.w};
      float bv[4] = {b.x, b.y, b.z, b.w};
#pragma unroll
      for (int i = 0; i < 4; ++i)
#pragma unroll
        for (int j = 0; j < 4; ++j) acc[i][j] += av[i] * bv[j];
    }
    __syncthreads();
  }
#pragma unroll
  for (int i = 0; i < 4; ++i) {
    int row = row0 + ty * 4 + i;
    float4 v = make_float4(acc[i][0], acc[i][1], acc[i][2], acc[i][3]);
    *(float4*)&O[(size_t)row * HSZ + tx * 4] = v;
  }
}

// ---------------------------------------------------------------------------
// Kernel 3: causal flash attention.  QB=32 q-rows/block, KB=64 kv-rows/tile.
// grid (64 q-tiles, 4 batches) = 256 blocks, 128 threads (16 tx x 8 ty).
// Online softmax state per thread for its 4 rows.
// ---------------------------------------------------------------------------
__global__ __launch_bounds__(128) void attn_kernel(const float* __restrict__ Q,
    const float* __restrict__ K, const float* __restrict__ V,
    float* __restrict__ Hd) {
  const int qt = blockIdx.x;      // 0..63
  const int b  = blockIdx.y;      // 0..3
  const int q0 = qt * 32;
  const float* Qb = Q + (size_t)b * T_SEQ * HSZ;
  const float* Kb = K + (size_t)b * T_SEQ * HSZ;
  const float* Vb = V + (size_t)b * T_SEQ * HSZ;

  __shared__ float Qt[64][36];   // [h][q]  stride 144B
  __shared__ float Kt[64][68];   // [h][k]  stride 272B
  __shared__ float Vs[64][68];   // [k][h]
  __shared__ float Pt[64][36];   // [k][q]

  const int tid = threadIdx.x;             // 0..127
  const int tx = tid & 15, ty = tid >> 4;  // tx: k/h col group, ty: q row group

  {   // stage Q^T (rows q0..q0+31)
    int c = tid & 15, r0 = tid >> 4;       // r0: 0..7
#pragma unroll
    for (int it = 0; it < 4; ++it) {
      int r = r0 + it * 8;
      float4 qv = *(const float4*)&Qb[(size_t)(q0 + r) * HSZ + c * 4];
      Qt[c * 4 + 0][r] = qv.x; Qt[c * 4 + 1][r] = qv.y;
      Qt[c * 4 + 2][r] = qv.z; Qt[c * 4 + 3][r] = qv.w;
    }
  }

  float m_[4], l_[4], o_[4][4];
#pragma unroll
  for (int i = 0; i < 4; ++i) {
    m_[i] = -1e30f; l_[i] = 0.f;
#pragma unroll
    for (int j = 0; j < 4; ++j) o_[i][j] = 0.f;
  }

  const int ntile = (qt >> 1) + 1;   // causal: kv tiles 0..(qt>>1)
  for (int kt = 0; kt < ntile; ++kt) {
    const int kv0 = kt * 64;
    {   // stage K^T and V (rows kv0..kv0+63)
      int c = tid & 15, r0 = tid >> 4;
#pragma unroll
      for (int it = 0; it < 8; ++it) {
        int r = r0 + it * 8;
        float4 kv = *(const float4*)&Kb[(size_t)(kv0 + r) * HSZ + c * 4];
        Kt[c * 4 + 0][r] = kv.x; Kt[c * 4 + 1][r] = kv.y;
        Kt[c * 4 + 2][r] = kv.z; Kt[c * 4 + 3][r] = kv.w;
        float4 vv = *(const float4*)&Vb[(size_t)(kv0 + r) * HSZ + c * 4];
        *(float4*)&Vs[r][c * 4] = vv;
      }
    }
    __syncthreads();   // staged tiles ready (also covers Qt on first iter)

    // S = (Q K^T) * 0.125, this thread: rows q0+ty*4+i, cols kv0+tx*4+j
    float s[4][4] = {};
#pragma unroll
    for (int h = 0; h < 64; ++h) {
      float4 a = *(const float4*)&Qt[h][ty * 4];
      float4 bb = *(const float4*)&Kt[h][tx * 4];
      float av[4] = {a.x, a.y, a.z, a.w};
      float bv[4] = {bb.x, bb.y, bb.z, bb.w};
#pragma unroll
      for (int i = 0; i < 4; ++i)
#pragma unroll
        for (int j = 0; j < 4; ++j) s[i][j] += av[i] * bv[j];
    }

    const bool diag = (kt == ntile - 1);
#pragma unroll
    for (int i = 0; i < 4; ++i) {
      const int grow = q0 + ty * 4 + i;
      float rmax = -1e30f;
#pragma unroll
      for (int j = 0; j < 4; ++j) {
        s[i][j] *= 0.125f;
        if (diag && (kv0 + tx * 4 + j > grow)) s[i][j] = -1e30f;
        rmax = fmaxf(rmax, s[i][j]);
      }
#pragma unroll
      for (int d = 1; d < 16; d <<= 1) rmax = fmaxf(rmax, __shfl_xor(rmax, d));
      const float mn = fmaxf(m_[i], rmax);
      const float sc = __expf(m_[i] - mn);
      float rsum = 0.f;
#pragma unroll
      for (int j = 0; j < 4; ++j) {
        s[i][j] = __expf(s[i][j] - mn);
        rsum += s[i][j];
      }
#pragma unroll
      for (int d = 1; d < 16; d <<= 1) rsum += __shfl_xor(rsum, d);
      l_[i] = l_[i] * sc + rsum;
      m_[i] = mn;
#pragma unroll
      for (int j = 0; j < 4; ++j) o_[i][j] *= sc;
    }

    // write P^T to LDS for the PV product
#pragma unroll
    for (int i = 0; i < 4; ++i)
#pragma unroll
      for (int j = 0; j < 4; ++j) Pt[tx * 4 + j][ty * 4 + i] = s[i][j];
    __syncthreads();   // Pt complete

    // O += P @ V : this thread rows q0+ty*4+i, cols h = tx*4+j
#pragma unroll
    for (int k = 0; k < 64; ++k) {
      float4 a = *(const float4*)&Pt[k][ty * 4];
      float4 bb = *(const float4*)&Vs[k][tx * 4];
      float av[4] = {a.x, a.y, a.z, a.w};
      float bv[4] = {bb.x, bb.y, bb.z, bb.w};
#pragma unroll
      for (int i = 0; i < 4; ++i)
#pragma unroll
        for (int j = 0; j < 4; ++j) o_[i][j] += av[i] * bv[j];
    }
    __syncthreads();   // done with Kt/Vs/Pt before next stage
  }

#pragma unroll
  for (int i = 0; i < 4; ++i) {
    const float inv = 1.f / l_[i];
    float4 v = make_float4(o_[i][0] * inv, o_[i][1] * inv,
                           o_[i][2] * inv, o_[i][3] * inv);
    *(float4*)&Hd[((size_t)b * T_SEQ + q0 + ty * 4 + i) * HSZ + tx * 4] = v;
  }
}

// ---------------------------------------------------------------------------
// Kernel 4: Out = Head @ Wpr + bp   ([8192 x 64] @ [64 x 1024])
// 64-row x 128-col tile per block, K=64 single pass. 4x8 reg tiles.
// ---------------------------------------------------------------------------
__global__ __launch_bounds__(256) void proj_kernel(const float* __restrict__ Hd,
    const float* __restrict__ Wpr, const float* __restrict__ bp,
    float* __restrict__ Out) {
  __shared__ float Ht[64][68];    // [k][r]
  __shared__ float Ws[64][132];   // [k][c]  stride 528B (16B aligned)
  const int tid = threadIdx.x;
  const int row0 = blockIdx.x * 64;
  const int c0 = blockIdx.y * 128;

  {   // stage H^T
    int c = tid & 15, r0 = tid >> 4;   // r0: 0..15
#pragma unroll
    for (int it = 0; it < 4; ++it) {
      int r = r0 + it * 16;
      float4 hv = *(const float4*)&Hd[(size_t)(row0 + r) * HSZ + c * 4];
      Ht[c * 4 + 0][r] = hv.x; Ht[c * 4 + 1][r] = hv.y;
      Ht[c * 4 + 2][r] = hv.z; Ht[c * 4 + 3][r] = hv.w;
    }
  }
  {   // stage Wpr tile [64][128]
    int c = tid & 31, r0 = tid >> 5;   // r0: 0..7
#pragma unroll
    for (int it = 0; it < 8; ++it) {
      int r = r0 + it * 8;
      *(float4*)&Ws[r][c * 4] =
          *(const float4*)&Wpr[(size_t)r * E_DIM + c0 + c * 4];
    }
  }
  __syncthreads();

  const int tx = tid & 15, ty = tid >> 4;
  float acc[4][8] = {};
#pragma unroll
  for (int k = 0; k < 64; ++k) {
    float4 a = *(const float4*)&Ht[k][ty * 4];
    float4 b0 = *(const float4*)&Ws[k][tx * 8];
    float4 b1 = *(const float4*)&Ws[k][tx * 8 + 4];
    float av[4] = {a.x, a.y, a.z, a.w};
    float bv[8] = {b0.x, b0.y, b0.z, b0.w, b1.x, b1.y, b1.z, b1.w};
#pragma unroll
    for (int i = 0; i < 4; ++i)
#pragma unroll
      for (int j = 0; j < 8; ++j) acc[i][j] += av[i] * bv[j];
  }

#pragma unroll
  for (int i = 0; i < 4; ++i) {
    const int row = row0 + ty * 4 + i;
    float4 v0, v1;
    v0.x = acc[i][0] + bp[c0 + tx * 8 + 0];
    v0.y = acc[i][1] + bp[c0 + tx * 8 + 1];
    v0.z = acc[i][2] + bp[c0 + tx * 8 + 2];
    v0.w = acc[i][3] + bp[c0 + tx * 8 + 3];
    v1.x = acc[i][4] + bp[c0 + tx * 8 + 4];
    v1.y = acc[i][5] + bp[c0 + tx * 8 + 5];
    v1.z = acc[i][6] + bp[c0 + tx * 8 + 6];
    v1.w = acc[i][7] + bp[c0 + tx * 8 + 7];
    *(float4*)&Out[(size_t)row * E_DIM + c0 + tx * 8] = v0;
    *(float4*)&Out[(size_t)row * E_DIM + c0 + tx * 8 + 4] = v1;
  }
}

// ---------------------------------------------------------------------------
extern "C" void kernel_launch(void* const* d_in, const int* in_sizes, int n_in,
                              void* d_out, int out_size, void* d_ws,
                              size_t ws_size, hipStream_t stream) {
  (void)in_sizes; (void)n_in; (void)out_size; (void)ws_size;
  const float* x  = (const float*)d_in[0];
  const float* Wq = (const float*)d_in[1];
  const float* Wk = (const float*)d_in[2];
  const float* Wv = (const float*)d_in[3];
  const float* Wp = (const float*)d_in[4];
  const float* bp = (const float*)d_in[5];
  float* out = (float*)d_out;

  // workspace layout (floats): Q,K,V,Head = 4*2048*64 each; Wpr = 64*1024
  float* ws  = (float*)d_ws;
  float* Q   = ws;
  float* K   = ws + 524288;
  float* V   = ws + 1048576;
  float* Hd  = ws + 1572864;
  float* Wpr = ws + 2097152;

  wpr_kernel<<<dim3(256), dim3(256), 0, stream>>>(Wp, Wpr);
  qkv_kernel<<<dim3(128, 3), dim3(256), 0, stream>>>(x, Wq, Wk, Wv, Q, K, V);
  attn_kernel<<<dim3(64, 4), dim3(128), 0, stream>>>(Q, K, V, Hd);
  proj_kernel<<<dim3(128, 8), dim3(256), 0, stream>>>(Hd, Wpr, bp, out);
}

// Round 4
// 293.809 us; speedup vs baseline: 1.6855x; 1.6855x over previous
//
#include <hip/hip_runtime.h>
#include <hip/hip_bf16.h>

#define T_SEQ 2048
#define E_DIM 1024
#define HSZ   64
#define NBAT  4
#define QB    64   // q-rows per attention block
#define NQT   32   // T_SEQ / QB

// ---------------------------------------------------------------------------
// Kernel 1: Wpr[j][f] = sum_{h=0..15} Wp[h*64+j][f]   (64 x 1024)
// The reference tiles one head 16x then projects; tiling folds into Wp rows.
// ---------------------------------------------------------------------------
__global__ __launch_bounds__(256) void wpr_kernel(const float* __restrict__ Wp,
                                                  float* __restrict__ Wpr) {
  int idx = blockIdx.x * 256 + threadIdx.x;   // 0..65535
  int f = idx & (E_DIM - 1);
  int j = idx >> 10;                          // 0..63
  float s = 0.f;
#pragma unroll
  for (int h = 0; h < 16; ++h) s += Wp[(size_t)(h * HSZ + j) * E_DIM + f];
  Wpr[idx] = s;
}

// ---------------------------------------------------------------------------
// Kernel 2: Q/K/V = X @ W   ([8192 x 1024] @ [1024 x 64])
// blockIdx.y selects Wq/Wk/Wv. 64x64 output tile, BK=32, 4x4 reg tiles.
// ---------------------------------------------------------------------------
__global__ __launch_bounds__(256) void qkv_kernel(const float* __restrict__ X,
    const float* __restrict__ Wq, const float* __restrict__ Wk,
    const float* __restrict__ Wv,
    float* __restrict__ Qo, float* __restrict__ Ko, float* __restrict__ Vo) {
  const float* W; float* O;
  if (blockIdx.y == 0)      { W = Wq; O = Qo; }
  else if (blockIdx.y == 1) { W = Wk; O = Ko; }
  else                      { W = Wv; O = Vo; }

  __shared__ float Xs[32][68];
  __shared__ float Ws[32][68];

  const int tid = threadIdx.x;
  const int tx = tid & 15, ty = tid >> 4;
  const int row0 = blockIdx.x * 64;

  float acc[4][4] = {};

  for (int k0 = 0; k0 < E_DIM; k0 += 32) {
    {
      int c = tid & 31, r0 = tid >> 5;
#pragma unroll
      for (int it = 0; it < 8; ++it) {
        int r = r0 + it * 8;
        Xs[c][r] = X[(size_t)(row0 + r) * E_DIM + k0 + c];
      }
    }
    {
      int c = tid & 63, r0 = tid >> 6;
#pragma unroll
      for (int it = 0; it < 8; ++it) {
        int r = r0 + it * 4;
        Ws[r][c] = W[(size_t)(k0 + r) * HSZ + c];
      }
    }
    __syncthreads();
#pragma unroll
    for (int kk = 0; kk < 32; ++kk) {
      float4 a = *(const float4*)&Xs[kk][ty * 4];
      float4 b = *(const float4*)&Ws[kk][tx * 4];
      float av[4] = {a.x, a.y, a.z, a.w};
      float bv[4] = {b.x, b.y, b.z, b.w};
#pragma unroll
      for (int i = 0; i < 4; ++i)
#pragma unroll
        for (int j = 0; j < 4; ++j) acc[i][j] += av[i] * bv[j];
    }
    __syncthreads();
  }
#pragma unroll
  for (int i = 0; i < 4; ++i) {
    int row = row0 + ty * 4 + i;
    float4 v = make_float4(acc[i][0], acc[i][1], acc[i][2], acc[i][3]);
    *(float4*)&O[(size_t)row * HSZ + tx * 4] = v;
  }
}

// ---------------------------------------------------------------------------
// Kernel 3a: split-K causal flash attention partials.
// grid (NQT, splits, NBAT), 256 threads (16x16 -> 4x4 reg tiles, 64x64 tile).
// Block (qt, sp, b) processes kv tiles [sp*n/splits, (sp+1)*n/splits) of the
// n = qt+1 tiles this q-tile needs; emits unnormalized (O, m, l) partial.
// ---------------------------------------------------------------------------
__global__ __launch_bounds__(256) void attn_part(const float* __restrict__ Q,
    const float* __restrict__ K, const float* __restrict__ V,
    float* __restrict__ Opart, float* __restrict__ mpart,
    float* __restrict__ lpart, int splits) {
  const int qt = blockIdx.x;        // 0..31
  const int sp = blockIdx.y;        // 0..splits-1
  const int b  = blockIdx.z;        // 0..3
  const int ntile = qt + 1;
  const int t0 = (sp * ntile) / splits;
  const int t1 = ((sp + 1) * ntile) / splits;
  const int q0 = qt * QB;
  const int pidx = (b * NQT + qt) * splits + sp;
  float* Op = Opart + (size_t)pidx * QB * HSZ;
  float* mp = mpart + (size_t)pidx * QB;
  float* lp = lpart + (size_t)pidx * QB;
  const int tid = threadIdx.x;

  if (t0 >= t1) {            // empty split: weight-0 sentinel (block-uniform)
    if (tid < QB) { mp[tid] = -1e30f; lp[tid] = 0.f; }
    return;
  }

  const float* Qb = Q + (size_t)b * T_SEQ * HSZ;
  const float* Kb = K + (size_t)b * T_SEQ * HSZ;
  const float* Vb = V + (size_t)b * T_SEQ * HSZ;

  __shared__ float Qt[64][68];   // [h][qrow]
  __shared__ float Kt[64][68];   // [h][kcol]
  __shared__ float Vs[64][68];   // [krow][h]
  __shared__ float Pt[64][68];   // [kcol][qrow]

  const int tx = tid & 15, ty = tid >> 4;   // 16 x 16

  {   // stage Q^T: rows q0..q0+63
    int c = tid & 15, r0 = tid >> 4;        // r0: 0..15
#pragma unroll
    for (int it = 0; it < 4; ++it) {
      int r = r0 + it * 16;
      float4 qv = *(const float4*)&Qb[(size_t)(q0 + r) * HSZ + c * 4];
      Qt[c * 4 + 0][r] = qv.x; Qt[c * 4 + 1][r] = qv.y;
      Qt[c * 4 + 2][r] = qv.z; Qt[c * 4 + 3][r] = qv.w;
    }
  }

  float m_[4], l_[4], o_[4][4];
#pragma unroll
  for (int i = 0; i < 4; ++i) {
    m_[i] = -1e30f; l_[i] = 0.f;
#pragma unroll
    for (int j = 0; j < 4; ++j) o_[i][j] = 0.f;
  }

  for (int kt = t0; kt < t1; ++kt) {
    const int kv0 = kt * 64;
    {   // stage K^T and V (rows kv0..kv0+63)
      int c = tid & 15, r0 = tid >> 4;
#pragma unroll
      for (int it = 0; it < 4; ++it) {
        int r = r0 + it * 16;
        float4 kv = *(const float4*)&Kb[(size_t)(kv0 + r) * HSZ + c * 4];
        Kt[c * 4 + 0][r] = kv.x; Kt[c * 4 + 1][r] = kv.y;
        Kt[c * 4 + 2][r] = kv.z; Kt[c * 4 + 3][r] = kv.w;
        float4 vv = *(const float4*)&Vb[(size_t)(kv0 + r) * HSZ + c * 4];
        *(float4*)&Vs[r][c * 4] = vv;
      }
    }
    __syncthreads();

    // S = (Q K^T) * 0.125 : rows q0+ty*4+i, cols kv0+tx*4+j
    float s[4][4] = {};
#pragma unroll
    for (int h = 0; h < 64; ++h) {
      float4 a = *(const float4*)&Qt[h][ty * 4];
      float4 bb = *(const float4*)&Kt[h][tx * 4];
      float av[4] = {a.x, a.y, a.z, a.w};
      float bv[4] = {bb.x, bb.y, bb.z, bb.w};
#pragma unroll
      for (int i = 0; i < 4; ++i)
#pragma unroll
        for (int j = 0; j < 4; ++j) s[i][j] += av[i] * bv[j];
    }

    const bool diag = (kt == qt);   // only the diagonal tile needs masking
#pragma unroll
    for (int i = 0; i < 4; ++i) {
      float rmax = -1e30f;
#pragma unroll
      for (int j = 0; j < 4; ++j) {
        s[i][j] *= 0.125f;
        if (diag && (tx * 4 + j > ty * 4 + i)) s[i][j] = -1e30f;
        rmax = fmaxf(rmax, s[i][j]);
      }
#pragma unroll
      for (int d = 1; d < 16; d <<= 1) rmax = fmaxf(rmax, __shfl_xor(rmax, d));
      const float mn = fmaxf(m_[i], rmax);
      const float sc = __expf(m_[i] - mn);
      float rsum = 0.f;
#pragma unroll
      for (int j = 0; j < 4; ++j) {
        s[i][j] = __expf(s[i][j] - mn);
        rsum += s[i][j];
      }
#pragma unroll
      for (int d = 1; d < 16; d <<= 1) rsum += __shfl_xor(rsum, d);
      l_[i] = l_[i] * sc + rsum;
      m_[i] = mn;
#pragma unroll
      for (int j = 0; j < 4; ++j) o_[i][j] *= sc;
    }

    // P^T to LDS for the PV product
#pragma unroll
    for (int i = 0; i < 4; ++i)
#pragma unroll
      for (int j = 0; j < 4; ++j) Pt[tx * 4 + j][ty * 4 + i] = s[i][j];
    __syncthreads();

    // O += P @ V
#pragma unroll
    for (int k = 0; k < 64; ++k) {
      float4 a = *(const float4*)&Pt[k][ty * 4];
      float4 bb = *(const float4*)&Vs[k][tx * 4];
      float av[4] = {a.x, a.y, a.z, a.w};
      float bv[4] = {bb.x, bb.y, bb.z, bb.w};
#pragma unroll
      for (int i = 0; i < 4; ++i)
#pragma unroll
        for (int j = 0; j < 4; ++j) o_[i][j] += av[i] * bv[j];
    }
    __syncthreads();
  }

  // write unnormalized partial
#pragma unroll
  for (int i = 0; i < 4; ++i) {
    const int r = ty * 4 + i;
    float4 v = make_float4(o_[i][0], o_[i][1], o_[i][2], o_[i][3]);
    *(float4*)&Op[(size_t)r * HSZ + tx * 4] = v;
    if (tx == 0) { mp[r] = m_[i]; lp[r] = l_[i]; }
  }
}

// ---------------------------------------------------------------------------
// Kernel 3b: combine partials -> head.  grid (NQT, NBAT), 256 threads.
// thread: row = tid>>2 (0..63), col group = (tid&3)*16 .. +15.
// ---------------------------------------------------------------------------
__global__ __launch_bounds__(256) void attn_combine(
    const float* __restrict__ Opart, const float* __restrict__ mpart,
    const float* __restrict__ lpart, float* __restrict__ Hd, int splits) {
  const int qt = blockIdx.x, b = blockIdx.y;
  const int row = threadIdx.x >> 2;
  const int c0 = (threadIdx.x & 3) * 16;
  const int pbase = (b * NQT + qt) * splits;

  float M = -1e30f;
  for (int s = 0; s < splits; ++s)
    M = fmaxf(M, mpart[(size_t)(pbase + s) * QB + row]);

  float L = 0.f;
  float acc[16];
#pragma unroll
  for (int c = 0; c < 16; ++c) acc[c] = 0.f;

  for (int s = 0; s < splits; ++s) {
    const float ms = mpart[(size_t)(pbase + s) * QB + row];
    const float ls = lpart[(size_t)(pbase + s) * QB + row];
    const float w = __expf(ms - M);
    L += w * ls;
    const float* Op = Opart + ((size_t)(pbase + s) * QB + row) * HSZ + c0;
#pragma unroll
    for (int cc = 0; cc < 16; cc += 4) {
      float4 v = *(const float4*)&Op[cc];
      acc[cc + 0] += w * v.x; acc[cc + 1] += w * v.y;
      acc[cc + 2] += w * v.z; acc[cc + 3] += w * v.w;
    }
  }

  const float inv = 1.f / L;
  float* dst = Hd + ((size_t)b * T_SEQ + qt * QB + row) * HSZ + c0;
#pragma unroll
  for (int cc = 0; cc < 16; cc += 4) {
    float4 v = make_float4(acc[cc] * inv, acc[cc + 1] * inv,
                           acc[cc + 2] * inv, acc[cc + 3] * inv);
    *(float4*)&dst[cc] = v;
  }
}

// ---------------------------------------------------------------------------
// Kernel 4: Out = Head @ Wpr + bp   ([8192 x 64] @ [64 x 1024])
// ---------------------------------------------------------------------------
__global__ __launch_bounds__(256) void proj_kernel(const float* __restrict__ Hd,
    const float* __restrict__ Wpr, const float* __restrict__ bp,
    float* __restrict__ Out) {
  __shared__ float Ht[64][68];
  __shared__ float Ws[64][132];
  const int tid = threadIdx.x;
  const int row0 = blockIdx.x * 64;
  const int c0 = blockIdx.y * 128;

  {
    int c = tid & 15, r0 = tid >> 4;
#pragma unroll
    for (int it = 0; it < 4; ++it) {
      int r = r0 + it * 16;
      float4 hv = *(const float4*)&Hd[(size_t)(row0 + r) * HSZ + c * 4];
      Ht[c * 4 + 0][r] = hv.x; Ht[c * 4 + 1][r] = hv.y;
      Ht[c * 4 + 2][r] = hv.z; Ht[c * 4 + 3][r] = hv.w;
    }
  }
  {
    int c = tid & 31, r0 = tid >> 5;
#pragma unroll
    for (int it = 0; it < 8; ++it) {
      int r = r0 + it * 8;
      *(float4*)&Ws[r][c * 4] =
          *(const float4*)&Wpr[(size_t)r * E_DIM + c0 + c * 4];
    }
  }
  __syncthreads();

  const int tx = tid & 15, ty = tid >> 4;
  float acc[4][8] = {};
#pragma unroll
  for (int k = 0; k < 64; ++k) {
    float4 a = *(const float4*)&Ht[k][ty * 4];
    float4 b0 = *(const float4*)&Ws[k][tx * 8];
    float4 b1 = *(const float4*)&Ws[k][tx * 8 + 4];
    float av[4] = {a.x, a.y, a.z, a.w};
    float bv[8] = {b0.x, b0.y, b0.z, b0.w, b1.x, b1.y, b1.z, b1.w};
#pragma unroll
    for (int i = 0; i < 4; ++i)
#pragma unroll
      for (int j = 0; j < 8; ++j) acc[i][j] += av[i] * bv[j];
  }

#pragma unroll
  for (int i = 0; i < 4; ++i) {
    const int row = row0 + ty * 4 + i;
    float4 v0, v1;
    v0.x = acc[i][0] + bp[c0 + tx * 8 + 0];
    v0.y = acc[i][1] + bp[c0 + tx * 8 + 1];
    v0.z = acc[i][2] + bp[c0 + tx * 8 + 2];
    v0.w = acc[i][3] + bp[c0 + tx * 8 + 3];
    v1.x = acc[i][4] + bp[c0 + tx * 8 + 4];
    v1.y = acc[i][5] + bp[c0 + tx * 8 + 5];
    v1.z = acc[i][6] + bp[c0 + tx * 8 + 6];
    v1.w = acc[i][7] + bp[c0 + tx * 8 + 7];
    *(float4*)&Out[(size_t)row * E_DIM + c0 + tx * 8] = v0;
    *(float4*)&Out[(size_t)row * E_DIM + c0 + tx * 8 + 4] = v1;
  }
}

// ---------------------------------------------------------------------------
extern "C" void kernel_launch(void* const* d_in, const int* in_sizes, int n_in,
                              void* d_out, int out_size, void* d_ws,
                              size_t ws_size, hipStream_t stream) {
  (void)in_sizes; (void)n_in; (void)out_size;
  const float* x  = (const float*)d_in[0];
  const float* Wq = (const float*)d_in[1];
  const float* Wk = (const float*)d_in[2];
  const float* Wv = (const float*)d_in[3];
  const float* Wp = (const float*)d_in[4];
  const float* bp = (const float*)d_in[5];
  float* out = (float*)d_out;

  // workspace (floats): Q,K,V,Head = 524288 each; Wpr = 65536; then partials.
  float* ws  = (float*)d_ws;
  float* Q   = ws;
  float* K   = ws + 524288;
  float* V   = ws + 1048576;
  float* Hd  = ws + 1572864;
  float* Wpr = ws + 2097152;
  const size_t base = 2162688;   // floats used so far

  // pick largest split count whose partials fit in ws (deterministic per run)
  int splits = 8;
  const size_t per_split = (size_t)NBAT * NQT * (QB * HSZ + 2 * QB); // floats
  while (splits > 1 && (base + per_split * splits) * 4 > ws_size) splits >>= 1;

  float* Opart = ws + base;                                   // [128*splits][64*64]
  float* mpart = Opart + (size_t)NBAT * NQT * splits * QB * HSZ;
  float* lpart = mpart + (size_t)NBAT * NQT * splits * QB;

  wpr_kernel<<<dim3(256), dim3(256), 0, stream>>>(Wp, Wpr);
  qkv_kernel<<<dim3(128, 3), dim3(256), 0, stream>>>(x, Wq, Wk, Wv, Q, K, V);
  attn_part<<<dim3(NQT, splits, NBAT), dim3(256), 0, stream>>>(
      Q, K, V, Opart, mpart, lpart, splits);
  attn_combine<<<dim3(NQT, NBAT), dim3(256), 0, stream>>>(
      Opart, mpart, lpart, Hd, splits);
  proj_kernel<<<dim3(128, 8), dim3(256), 0, stream>>>(Hd, Wpr, bp, out);
}

// Round 5
// 220.979 us; speedup vs baseline: 2.2410x; 1.3296x over previous
//
#include <hip/hip_runtime.h>
#include <hip/hip_bf16.h>

#define T_SEQ 2048
#define E_DIM 1024
#define HSZ   64
#define NBAT  4
#define QB    64   // q-rows per attention block
#define NQT   32   // T_SEQ / QB

typedef __attribute__((ext_vector_type(8))) short short8;
typedef __attribute__((ext_vector_type(4))) float f32x4;

__device__ inline short f2bf(float f) {   // fp32 -> bf16 RNE
  union { float f; unsigned u; } v; v.f = f;
  unsigned r = v.u + 0x7FFFu + ((v.u >> 16) & 1u);
  return (short)(r >> 16);
}

// ---------------------------------------------------------------------------
// Kernel 1: Wpr[j][f] = sum_{h=0..15} Wp[h*64+j][f]   (64 x 1024)
// ---------------------------------------------------------------------------
__global__ __launch_bounds__(256) void wpr_kernel(const float* __restrict__ Wp,
                                                  float* __restrict__ Wpr) {
  int idx = blockIdx.x * 256 + threadIdx.x;
  int f = idx & (E_DIM - 1);
  int j = idx >> 10;
  float s = 0.f;
#pragma unroll
  for (int h = 0; h < 16; ++h) s += Wp[(size_t)(h * HSZ + j) * E_DIM + f];
  Wpr[idx] = s;
}

// ---------------------------------------------------------------------------
// Kernel 2: Q/K/V = X @ W.  V is emitted TRANSPOSED: Vt[b][hd][t]
// (attention's PV B-fragment wants [hd][kv]; L2 write-combines the scatter).
// ---------------------------------------------------------------------------
__global__ __launch_bounds__(256) void qkv_kernel(const float* __restrict__ X,
    const float* __restrict__ Wq, const float* __restrict__ Wk,
    const float* __restrict__ Wv,
    float* __restrict__ Qo, float* __restrict__ Ko, float* __restrict__ Vt) {
  const float* W;
  if (blockIdx.y == 0)      W = Wq;
  else if (blockIdx.y == 1) W = Wk;
  else                      W = Wv;

  __shared__ float Xs[32][68];
  __shared__ float Ws[32][68];

  const int tid = threadIdx.x;
  const int tx = tid & 15, ty = tid >> 4;
  const int row0 = blockIdx.x * 64;

  float acc[4][4] = {};

  for (int k0 = 0; k0 < E_DIM; k0 += 32) {
    {
      int c = tid & 31, r0 = tid >> 5;
#pragma unroll
      for (int it = 0; it < 8; ++it) {
        int r = r0 + it * 8;
        Xs[c][r] = X[(size_t)(row0 + r) * E_DIM + k0 + c];
      }
    }
    {
      int c = tid & 63, r0 = tid >> 6;
#pragma unroll
      for (int it = 0; it < 8; ++it) {
        int r = r0 + it * 4;
        Ws[r][c] = W[(size_t)(k0 + r) * HSZ + c];
      }
    }
    __syncthreads();
#pragma unroll
    for (int kk = 0; kk < 32; ++kk) {
      float4 a = *(const float4*)&Xs[kk][ty * 4];
      float4 b = *(const float4*)&Ws[kk][tx * 4];
      float av[4] = {a.x, a.y, a.z, a.w};
      float bv[4] = {b.x, b.y, b.z, b.w};
#pragma unroll
      for (int i = 0; i < 4; ++i)
#pragma unroll
        for (int j = 0; j < 4; ++j) acc[i][j] += av[i] * bv[j];
    }
    __syncthreads();
  }

  if (blockIdx.y == 2) {      // V^T store: Vt[b][hd][t]
    const int bb = row0 >> 11;
    const int tbase = (row0 & 2047) + ty * 4;
#pragma unroll
    for (int i = 0; i < 4; ++i)
#pragma unroll
      for (int j = 0; j < 4; ++j)
        Vt[(size_t)bb * HSZ * T_SEQ + (size_t)(tx * 4 + j) * T_SEQ + tbase + i] =
            acc[i][j];
  } else {
    float* O = (blockIdx.y == 0) ? Qo : Ko;
#pragma unroll
    for (int i = 0; i < 4; ++i) {
      int row = row0 + ty * 4 + i;
      float4 v = make_float4(acc[i][0], acc[i][1], acc[i][2], acc[i][3]);
      *(float4*)&O[(size_t)row * HSZ + tx * 4] = v;
    }
  }
}

// ---------------------------------------------------------------------------
// Kernel 3a: split-K causal flash attention partials, bf16 MFMA.
// grid (NQT, splits, NBAT), 256 threads = 4 warps; warp w owns q-rows
// q0+16w..+15.  mfma_f32_16x16x32_bf16:
//   A-frag: lane = [m = l&15][k = 8*(l>>4)+j]   (8 consecutive k per lane)
//   B-frag: lane = [n = l&15][k = 8*(l>>4)+j]
//   C/D   : col n = l&15, row m = (l>>4)*4+reg            (m89-verified)
// LDS tiles swizzled: 16B chunk index ^= (row&7)  (G4 fix for 128B stride).
// ---------------------------------------------------------------------------
__global__ __launch_bounds__(256) void attn_part(const float* __restrict__ Q,
    const float* __restrict__ K, const float* __restrict__ Vt,
    float* __restrict__ Opart, float* __restrict__ mpart,
    float* __restrict__ lpart, int splits) {
  const int qt = blockIdx.x;
  const int sp = blockIdx.y;
  const int b  = blockIdx.z;
  const int ntile = qt + 1;
  const int t0 = (sp * ntile) / splits;
  const int t1 = ((sp + 1) * ntile) / splits;
  const int q0 = qt * QB;
  const int pidx = (b * NQT + qt) * splits + sp;
  float* Op = Opart + (size_t)pidx * QB * HSZ;
  float* mp = mpart + (size_t)pidx * QB;
  float* lp = lpart + (size_t)pidx * QB;
  const int tid = threadIdx.x;

  if (t0 >= t1) {
    if (tid < QB) { mp[tid] = -1e30f; lp[tid] = 0.f; }
    return;
  }

  const float* Qb  = Q  + (size_t)b * T_SEQ * HSZ;
  const float* Kb  = K  + (size_t)b * T_SEQ * HSZ;
  const float* Vtb = Vt + (size_t)b * HSZ * T_SEQ;

  __shared__ short Ks[64 * 64];        // [kv][hd] bf16, chunk-swizzled
  __shared__ short Vs[64 * 64];        // [hd][kv] bf16, chunk-swizzled
  __shared__ short Ps[4][16 * 64];     // per-warp P [q][kv], chunk-swizzled

  const int lane = tid & 63;
  const int w    = tid >> 6;
  const int l15  = lane & 15;
  const int l4   = lane >> 4;          // 0..3

  // hoist Q fragments to registers: rows q0+16w+(l&15), k = 8*l4+j (+32*ks)
  short8 qf[2];
  {
    const float* qsrc = &Qb[(size_t)(q0 + w * 16 + l15) * HSZ + l4 * 8];
#pragma unroll
    for (int ks = 0; ks < 2; ++ks) {
      float4 a = *(const float4*)(qsrc + ks * 32);
      float4 c = *(const float4*)(qsrc + ks * 32 + 4);
      short8 f;
      f[0] = f2bf(a.x); f[1] = f2bf(a.y); f[2] = f2bf(a.z); f[3] = f2bf(a.w);
      f[4] = f2bf(c.x); f[5] = f2bf(c.y); f[6] = f2bf(c.z); f[7] = f2bf(c.w);
      qf[ks] = f;
    }
  }

  f32x4 o[4];
  float m_[4], l_[4];
#pragma unroll
  for (int i = 0; i < 4; ++i) {
    o[i] = (f32x4)0.f; m_[i] = -1e30f; l_[i] = 0.f;
  }

  for (int kt = t0; kt < t1; ++kt) {
    const int kv0 = kt * 64;
    // ---- stage K (row=kv) and V^T (row=hd), bf16 + chunk swizzle ----
#pragma unroll
    for (int ci = tid; ci < 512; ci += 256) {
      int r = ci >> 3, c = ci & 7;
      const float* s = &Kb[(size_t)(kv0 + r) * HSZ + c * 8];
      float4 a = *(const float4*)s, d = *(const float4*)(s + 4);
      short8 f;
      f[0] = f2bf(a.x); f[1] = f2bf(a.y); f[2] = f2bf(a.z); f[3] = f2bf(a.w);
      f[4] = f2bf(d.x); f[5] = f2bf(d.y); f[6] = f2bf(d.z); f[7] = f2bf(d.w);
      *(short8*)&Ks[r * 64 + ((c ^ (r & 7)) * 8)] = f;
    }
#pragma unroll
    for (int ci = tid; ci < 512; ci += 256) {
      int r = ci >> 3, c = ci & 7;   // r = hd, c = kv chunk
      const float* s = &Vtb[(size_t)r * T_SEQ + kv0 + c * 8];
      float4 a = *(const float4*)s, d = *(const float4*)(s + 4);
      short8 f;
      f[0] = f2bf(a.x); f[1] = f2bf(a.y); f[2] = f2bf(a.z); f[3] = f2bf(a.w);
      f[4] = f2bf(d.x); f[5] = f2bf(d.y); f[6] = f2bf(d.z); f[7] = f2bf(d.w);
      *(short8*)&Vs[r * 64 + ((c ^ (r & 7)) * 8)] = f;
    }
    __syncthreads();

    // ---- S = Q K^T (per warp: 16 q-rows x 64 kv-cols) ----
    f32x4 sacc[4];
#pragma unroll
    for (int nb = 0; nb < 4; ++nb) sacc[nb] = (f32x4)0.f;
#pragma unroll
    for (int nb = 0; nb < 4; ++nb) {
      const int krow = nb * 16 + l15;
#pragma unroll
      for (int ks = 0; ks < 2; ++ks) {
        short8 kf = *(short8*)&Ks[krow * 64 + (((ks * 4 + l4) ^ (krow & 7)) * 8)];
        sacc[nb] = __builtin_amdgcn_mfma_f32_16x16x32_bf16(qf[ks], kf, sacc[nb],
                                                           0, 0, 0);
      }
    }

    // ---- online softmax (rows = (l>>4)*4+reg, cols = nb*16 + l&15) ----
    const bool diag = (kt == qt);
#pragma unroll
    for (int reg = 0; reg < 4; ++reg) {
      const int grow = q0 + w * 16 + l4 * 4 + reg;
      float sv[4];
      float rmax = -1e30f;
#pragma unroll
      for (int nb = 0; nb < 4; ++nb) {
        sv[nb] = sacc[nb][reg] * 0.125f;
        if (diag && (kv0 + nb * 16 + l15 > grow)) sv[nb] = -1e30f;
        rmax = fmaxf(rmax, sv[nb]);
      }
#pragma unroll
      for (int d = 1; d < 16; d <<= 1) rmax = fmaxf(rmax, __shfl_xor(rmax, d));
      const float mn = fmaxf(m_[reg], rmax);
      const float sc = __expf(m_[reg] - mn);
      float rsum = 0.f;
#pragma unroll
      for (int nb = 0; nb < 4; ++nb) {
        sv[nb] = __expf(sv[nb] - mn);
        rsum += sv[nb];
      }
#pragma unroll
      for (int d = 1; d < 16; d <<= 1) rsum += __shfl_xor(rsum, d);
      l_[reg] = l_[reg] * sc + rsum;
      m_[reg] = mn;
#pragma unroll
      for (int hb = 0; hb < 4; ++hb) o[hb][reg] *= sc;
      // P -> per-warp LDS (bf16, swizzled), row=(l>>4)*4+reg, col=nb*16+l15
      const int prow = l4 * 4 + reg;
#pragma unroll
      for (int nb = 0; nb < 4; ++nb) {
        const int col = nb * 16 + l15;
        Ps[w][prow * 64 + (((col >> 3) ^ (prow & 7)) * 8) + (col & 7)] =
            f2bf(sv[nb]);
      }
    }

    // ---- O += P @ V ----
#pragma unroll
    for (int ks = 0; ks < 2; ++ks) {
      const int prow = l15;
      short8 pf = *(short8*)&Ps[w][prow * 64 + (((ks * 4 + l4) ^ (prow & 7)) * 8)];
#pragma unroll
      for (int hb = 0; hb < 4; ++hb) {
        const int vrow = hb * 16 + l15;
        short8 vf = *(short8*)&Vs[vrow * 64 + (((ks * 4 + l4) ^ (vrow & 7)) * 8)];
        o[hb] = __builtin_amdgcn_mfma_f32_16x16x32_bf16(pf, vf, o[hb], 0, 0, 0);
      }
    }
    __syncthreads();
  }

  // ---- write unnormalized partial (C/D layout) ----
#pragma unroll
  for (int hb = 0; hb < 4; ++hb)
#pragma unroll
    for (int reg = 0; reg < 4; ++reg)
      Op[(size_t)(w * 16 + l4 * 4 + reg) * HSZ + hb * 16 + l15] = o[hb][reg];
  if (l15 == 0) {
#pragma unroll
    for (int reg = 0; reg < 4; ++reg) {
      mp[w * 16 + l4 * 4 + reg] = m_[reg];
      lp[w * 16 + l4 * 4 + reg] = l_[reg];
    }
  }
}

// ---------------------------------------------------------------------------
// Kernel 3b: combine partials -> head.  grid (NQT, NBAT), 256 threads.
// ---------------------------------------------------------------------------
__global__ __launch_bounds__(256) void attn_combine(
    const float* __restrict__ Opart, const float* __restrict__ mpart,
    const float* __restrict__ lpart, float* __restrict__ Hd, int splits) {
  const int qt = blockIdx.x, b = blockIdx.y;
  const int row = threadIdx.x >> 2;
  const int c0 = (threadIdx.x & 3) * 16;
  const int pbase = (b * NQT + qt) * splits;

  float M = -1e30f;
  for (int s = 0; s < splits; ++s)
    M = fmaxf(M, mpart[(size_t)(pbase + s) * QB + row]);

  float L = 0.f;
  float acc[16];
#pragma unroll
  for (int c = 0; c < 16; ++c) acc[c] = 0.f;

  for (int s = 0; s < splits; ++s) {
    const float ms = mpart[(size_t)(pbase + s) * QB + row];
    const float ls = lpart[(size_t)(pbase + s) * QB + row];
    const float w = __expf(ms - M);
    L += w * ls;
    const float* Op = Opart + ((size_t)(pbase + s) * QB + row) * HSZ + c0;
#pragma unroll
    for (int cc = 0; cc < 16; cc += 4) {
      float4 v = *(const float4*)&Op[cc];
      acc[cc + 0] += w * v.x; acc[cc + 1] += w * v.y;
      acc[cc + 2] += w * v.z; acc[cc + 3] += w * v.w;
    }
  }

  const float inv = 1.f / L;
  float* dst = Hd + ((size_t)b * T_SEQ + qt * QB + row) * HSZ + c0;
#pragma unroll
  for (int cc = 0; cc < 16; cc += 4) {
    float4 v = make_float4(acc[cc] * inv, acc[cc + 1] * inv,
                           acc[cc + 2] * inv, acc[cc + 3] * inv);
    *(float4*)&dst[cc] = v;
  }
}

// ---------------------------------------------------------------------------
// Kernel 4: Out = Head @ Wpr + bp   ([8192 x 64] @ [64 x 1024])
// ---------------------------------------------------------------------------
__global__ __launch_bounds__(256) void proj_kernel(const float* __restrict__ Hd,
    const float* __restrict__ Wpr, const float* __restrict__ bp,
    float* __restrict__ Out) {
  __shared__ float Ht[64][68];
  __shared__ float Ws[64][132];
  const int tid = threadIdx.x;
  const int row0 = blockIdx.x * 64;
  const int c0 = blockIdx.y * 128;

  {
    int c = tid & 15, r0 = tid >> 4;
#pragma unroll
    for (int it = 0; it < 4; ++it) {
      int r = r0 + it * 16;
      float4 hv = *(const float4*)&Hd[(size_t)(row0 + r) * HSZ + c * 4];
      Ht[c * 4 + 0][r] = hv.x; Ht[c * 4 + 1][r] = hv.y;
      Ht[c * 4 + 2][r] = hv.z; Ht[c * 4 + 3][r] = hv.w;
    }
  }
  {
    int c = tid & 31, r0 = tid >> 5;
#pragma unroll
    for (int it = 0; it < 8; ++it) {
      int r = r0 + it * 8;
      *(float4*)&Ws[r][c * 4] =
          *(const float4*)&Wpr[(size_t)r * E_DIM + c0 + c * 4];
    }
  }
  __syncthreads();

  const int tx = tid & 15, ty = tid >> 4;
  float acc[4][8] = {};
#pragma unroll
  for (int k = 0; k < 64; ++k) {
    float4 a = *(const float4*)&Ht[k][ty * 4];
    float4 b0 = *(const float4*)&Ws[k][tx * 8];
    float4 b1 = *(const float4*)&Ws[k][tx * 8 + 4];
    float av[4] = {a.x, a.y, a.z, a.w};
    float bv[8] = {b0.x, b0.y, b0.z, b0.w, b1.x, b1.y, b1.z, b1.w};
#pragma unroll
    for (int i = 0; i < 4; ++i)
#pragma unroll
      for (int j = 0; j < 8; ++j) acc[i][j] += av[i] * bv[j];
  }

#pragma unroll
  for (int i = 0; i < 4; ++i) {
    const int row = row0 + ty * 4 + i;
    float4 v0, v1;
    v0.x = acc[i][0] + bp[c0 + tx * 8 + 0];
    v0.y = acc[i][1] + bp[c0 + tx * 8 + 1];
    v0.z = acc[i][2] + bp[c0 + tx * 8 + 2];
    v0.w = acc[i][3] + bp[c0 + tx * 8 + 3];
    v1.x = acc[i][4] + bp[c0 + tx * 8 + 4];
    v1.y = acc[i][5] + bp[c0 + tx * 8 + 5];
    v1.z = acc[i][6] + bp[c0 + tx * 8 + 6];
    v1.w = acc[i][7] + bp[c0 + tx * 8 + 7];
    *(float4*)&Out[(size_t)row * E_DIM + c0 + tx * 8] = v0;
    *(float4*)&Out[(size_t)row * E_DIM + c0 + tx * 8 + 4] = v1;
  }
}

// ---------------------------------------------------------------------------
extern "C" void kernel_launch(void* const* d_in, const int* in_sizes, int n_in,
                              void* d_out, int out_size, void* d_ws,
                              size_t ws_size, hipStream_t stream) {
  (void)in_sizes; (void)n_in; (void)out_size;
  const float* x  = (const float*)d_in[0];
  const float* Wq = (const float*)d_in[1];
  const float* Wk = (const float*)d_in[2];
  const float* Wv = (const float*)d_in[3];
  const float* Wp = (const float*)d_in[4];
  const float* bp = (const float*)d_in[5];
  float* out = (float*)d_out;

  float* ws  = (float*)d_ws;
  float* Q   = ws;
  float* K   = ws + 524288;
  float* Vt  = ws + 1048576;   // transposed: [b][hd][t]
  float* Hd  = ws + 1572864;
  float* Wpr = ws + 2097152;
  const size_t base = 2162688;

  int splits = 8;
  const size_t per_split = (size_t)NBAT * NQT * (QB * HSZ + 2 * QB);
  while (splits > 1 && (base + per_split * splits) * 4 > ws_size) splits >>= 1;

  float* Opart = ws + base;
  float* mpart = Opart + (size_t)NBAT * NQT * splits * QB * HSZ;
  float* lpart = mpart + (size_t)NBAT * NQT * splits * QB;

  wpr_kernel<<<dim3(256), dim3(256), 0, stream>>>(Wp, Wpr);
  qkv_kernel<<<dim3(128, 3), dim3(256), 0, stream>>>(x, Wq, Wk, Wv, Q, K, Vt);
  attn_part<<<dim3(NQT, splits, NBAT), dim3(256), 0, stream>>>(
      Q, K, Vt, Opart, mpart, lpart, splits);
  attn_combine<<<dim3(NQT, NBAT), dim3(256), 0, stream>>>(
      Opart, mpart, lpart, Hd, splits);
  proj_kernel<<<dim3(128, 8), dim3(256), 0, stream>>>(Hd, Wpr, bp, out);
}

// Round 6
// 157.599 us; speedup vs baseline: 3.1422x; 1.4022x over previous
//
#include <hip/hip_runtime.h>
#include <hip/hip_bf16.h>

#define T_SEQ 2048
#define E_DIM 1024
#define HSZ   64
#define NBAT  4
#define QB    64   // q-rows per attention block
#define NQT   32   // T_SEQ / QB

typedef __attribute__((ext_vector_type(8))) short short8;
typedef __attribute__((ext_vector_type(4))) float f32x4;

__device__ inline short f2bf(float f) {   // fp32 -> bf16 RNE
  union { float f; unsigned u; } v; v.f = f;
  unsigned r = v.u + 0x7FFFu + ((v.u >> 16) & 1u);
  return (short)(r >> 16);
}

// ---------------------------------------------------------------------------
// Kernel 1: Wpr[j][f] = sum_{h=0..15} Wp[h*64+j][f]   (64 x 1024)
// ---------------------------------------------------------------------------
__global__ __launch_bounds__(256) void wpr_kernel(const float* __restrict__ Wp,
                                                  float* __restrict__ Wpr) {
  int idx = blockIdx.x * 256 + threadIdx.x;
  int f = idx & (E_DIM - 1);
  int j = idx >> 10;
  float s = 0.f;
#pragma unroll
  for (int h = 0; h < 16; ++h) s += Wp[(size_t)(h * HSZ + j) * E_DIM + f];
  Wpr[idx] = s;
}

// ---------------------------------------------------------------------------
// Kernel 1b: Wt[kt][n][kk] = bf16(Wsel[kt*64+kk][n&63]),  n in [0,192)
// sel = n>>6 picks Wq/Wk/Wv.  B-fragment-ready layout for qkv_mfma.
// ---------------------------------------------------------------------------
__global__ __launch_bounds__(256) void wt_kernel(const float* __restrict__ Wq,
    const float* __restrict__ Wk, const float* __restrict__ Wv,
    short* __restrict__ Wt) {
  int idx = blockIdx.x * 256 + threadIdx.x;   // 0..196607
  int kk = idx & 63;
  int tmp = idx >> 6;
  int kt = tmp / 192;
  int n = tmp - kt * 192;
  const float* W = (n < 64) ? Wq : (n < 128) ? Wk : Wv;
  Wt[idx] = f2bf(W[(size_t)(kt * 64 + kk) * HSZ + (n & 63)]);
}

// ---------------------------------------------------------------------------
// Kernel 2: fused QKV, bf16 MFMA.  C[8192 x 192] = X @ [Wq|Wk|Wv].
// 16-row M-tiles -> 512 blocks.  4 warps x 3 n-blocks (48 cols) each.
// Outputs bf16: Q,K row-major [b*t][hs]; V transposed [b][hd][t].
// LDS chunk-swizzle (16B chunk idx ^= row&7) throughout.
// ---------------------------------------------------------------------------
__global__ __launch_bounds__(256) void qkv_mfma(const float* __restrict__ X,
    const short* __restrict__ Wt, short* __restrict__ Qo,
    short* __restrict__ Ko, short* __restrict__ Vt) {
  __shared__ short Xs[16 * 64];    // [m][k] swizzled
  __shared__ short Ws[192 * 64];   // [n][k] swizzled

  const int tid = threadIdx.x;
  const int m0 = blockIdx.x * 16;
  const int lane = tid & 63, w = tid >> 6;
  const int l15 = lane & 15, l4 = lane >> 4;

  f32x4 acc[3];
  acc[0] = (f32x4)0.f; acc[1] = (f32x4)0.f; acc[2] = (f32x4)0.f;

  for (int kt = 0; kt < 16; ++kt) {
    const int k0 = kt * 64;
    if (tid < 128) {   // stage X tile: 16 rows x 8 chunks
      int r = tid >> 3, c = tid & 7;
      const float* s = &X[(size_t)(m0 + r) * E_DIM + k0 + c * 8];
      float4 a = *(const float4*)s, d = *(const float4*)(s + 4);
      short8 f;
      f[0] = f2bf(a.x); f[1] = f2bf(a.y); f[2] = f2bf(a.z); f[3] = f2bf(a.w);
      f[4] = f2bf(d.x); f[5] = f2bf(d.y); f[6] = f2bf(d.z); f[7] = f2bf(d.w);
      *(short8*)&Xs[r * 64 + ((c ^ (r & 7)) * 8)] = f;
    }
    {   // stage W panel: 192 rows x 8 chunks = 1536, contiguous source
      const short* wsrc = Wt + (size_t)kt * 12288;
#pragma unroll
      for (int i = 0; i < 6; ++i) {
        int ci = tid + i * 256;
        int r = ci >> 3, c = ci & 7;
        short8 f = *(const short8*)&wsrc[ci * 8];
        *(short8*)&Ws[r * 64 + ((c ^ (r & 7)) * 8)] = f;
      }
    }
    __syncthreads();
#pragma unroll
    for (int ks = 0; ks < 2; ++ks) {
      short8 af = *(short8*)&Xs[l15 * 64 + (((ks * 4 + l4) ^ (l15 & 7)) * 8)];
#pragma unroll
      for (int i = 0; i < 3; ++i) {
        int n = (w * 3 + i) * 16 + l15;
        short8 bf = *(short8*)&Ws[n * 64 + (((ks * 4 + l4) ^ (n & 7)) * 8)];
        acc[i] = __builtin_amdgcn_mfma_f32_16x16x32_bf16(af, bf, acc[i], 0, 0, 0);
      }
    }
    __syncthreads();
  }

  // epilogue: C/D layout col=l15, row=l4*4+reg
  const int b = m0 >> 11, t = m0 & 2047;
#pragma unroll
  for (int i = 0; i < 3; ++i) {
    const int nb = w * 3 + i;             // 0..11
    const int col = (nb & 3) * 16 + l15;  // 0..63 within Q/K/V
    const int sel = nb >> 2;
#pragma unroll
    for (int reg = 0; reg < 4; ++reg) {
      const int row = l4 * 4 + reg;
      short v = f2bf(acc[i][reg]);
      if (sel == 0)      Qo[(size_t)(m0 + row) * HSZ + col] = v;
      else if (sel == 1) Ko[(size_t)(m0 + row) * HSZ + col] = v;
      else               Vt[((size_t)b * HSZ + col) * T_SEQ + t + row] = v;
    }
  }
}

// ---------------------------------------------------------------------------
// Kernel 3a: split-K causal flash attention partials, bf16 MFMA.
// Inputs now bf16 (Q,K row-major; Vt [b][hd][t]).  Layouts as round 5.
// ---------------------------------------------------------------------------
__global__ __launch_bounds__(256) void attn_part(const short* __restrict__ Q,
    const short* __restrict__ K, const short* __restrict__ Vt,
    float* __restrict__ Opart, float* __restrict__ mpart,
    float* __restrict__ lpart, int splits) {
  const int qt = blockIdx.x;
  const int sp = blockIdx.y;
  const int b  = blockIdx.z;
  const int ntile = qt + 1;
  const int t0 = (sp * ntile) / splits;
  const int t1 = ((sp + 1) * ntile) / splits;
  const int q0 = qt * QB;
  const int pidx = (b * NQT + qt) * splits + sp;
  float* Op = Opart + (size_t)pidx * QB * HSZ;
  float* mp = mpart + (size_t)pidx * QB;
  float* lp = lpart + (size_t)pidx * QB;
  const int tid = threadIdx.x;

  if (t0 >= t1) {
    if (tid < QB) { mp[tid] = -1e30f; lp[tid] = 0.f; }
    return;
  }

  const short* Qb  = Q  + (size_t)b * T_SEQ * HSZ;
  const short* Kb  = K  + (size_t)b * T_SEQ * HSZ;
  const short* Vtb = Vt + (size_t)b * HSZ * T_SEQ;

  __shared__ short Ks[64 * 64];
  __shared__ short Vs[64 * 64];
  __shared__ short Ps[4][16 * 64];

  const int lane = tid & 63;
  const int w    = tid >> 6;
  const int l15  = lane & 15;
  const int l4   = lane >> 4;

  short8 qf[2];
#pragma unroll
  for (int ks = 0; ks < 2; ++ks)
    qf[ks] = *(const short8*)&Qb[(size_t)(q0 + w * 16 + l15) * HSZ + ks * 32 + l4 * 8];

  f32x4 o[4];
  float m_[4], l_[4];
#pragma unroll
  for (int i = 0; i < 4; ++i) { o[i] = (f32x4)0.f; m_[i] = -1e30f; l_[i] = 0.f; }

  for (int kt = t0; kt < t1; ++kt) {
    const int kv0 = kt * 64;
#pragma unroll
    for (int ci = tid; ci < 512; ci += 256) {   // K: [kv][hd]
      int r = ci >> 3, c = ci & 7;
      short8 f = *(const short8*)&Kb[(size_t)(kv0 + r) * HSZ + c * 8];
      *(short8*)&Ks[r * 64 + ((c ^ (r & 7)) * 8)] = f;
    }
#pragma unroll
    for (int ci = tid; ci < 512; ci += 256) {   // V^T: [hd][kv]
      int r = ci >> 3, c = ci & 7;
      short8 f = *(const short8*)&Vtb[(size_t)r * T_SEQ + kv0 + c * 8];
      *(short8*)&Vs[r * 64 + ((c ^ (r & 7)) * 8)] = f;
    }
    __syncthreads();

    f32x4 sacc[4];
#pragma unroll
    for (int nb = 0; nb < 4; ++nb) sacc[nb] = (f32x4)0.f;
#pragma unroll
    for (int nb = 0; nb < 4; ++nb) {
      const int krow = nb * 16 + l15;
#pragma unroll
      for (int ks = 0; ks < 2; ++ks) {
        short8 kf = *(short8*)&Ks[krow * 64 + (((ks * 4 + l4) ^ (krow & 7)) * 8)];
        sacc[nb] = __builtin_amdgcn_mfma_f32_16x16x32_bf16(qf[ks], kf, sacc[nb],
                                                           0, 0, 0);
      }
    }

    const bool diag = (kt == qt);
#pragma unroll
    for (int reg = 0; reg < 4; ++reg) {
      const int grow = q0 + w * 16 + l4 * 4 + reg;
      float sv[4];
      float rmax = -1e30f;
#pragma unroll
      for (int nb = 0; nb < 4; ++nb) {
        sv[nb] = sacc[nb][reg] * 0.125f;
        if (diag && (kv0 + nb * 16 + l15 > grow)) sv[nb] = -1e30f;
        rmax = fmaxf(rmax, sv[nb]);
      }
#pragma unroll
      for (int d = 1; d < 16; d <<= 1) rmax = fmaxf(rmax, __shfl_xor(rmax, d));
      const float mn = fmaxf(m_[reg], rmax);
      const float sc = __expf(m_[reg] - mn);
      float rsum = 0.f;
#pragma unroll
      for (int nb = 0; nb < 4; ++nb) {
        sv[nb] = __expf(sv[nb] - mn);
        rsum += sv[nb];
      }
#pragma unroll
      for (int d = 1; d < 16; d <<= 1) rsum += __shfl_xor(rsum, d);
      l_[reg] = l_[reg] * sc + rsum;
      m_[reg] = mn;
#pragma unroll
      for (int hb = 0; hb < 4; ++hb) o[hb][reg] *= sc;
      const int prow = l4 * 4 + reg;
#pragma unroll
      for (int nb = 0; nb < 4; ++nb) {
        const int col = nb * 16 + l15;
        Ps[w][prow * 64 + (((col >> 3) ^ (prow & 7)) * 8) + (col & 7)] =
            f2bf(sv[nb]);
      }
    }

#pragma unroll
    for (int ks = 0; ks < 2; ++ks) {
      const int prow = l15;
      short8 pf = *(short8*)&Ps[w][prow * 64 + (((ks * 4 + l4) ^ (prow & 7)) * 8)];
#pragma unroll
      for (int hb = 0; hb < 4; ++hb) {
        const int vrow = hb * 16 + l15;
        short8 vf = *(short8*)&Vs[vrow * 64 + (((ks * 4 + l4) ^ (vrow & 7)) * 8)];
        o[hb] = __builtin_amdgcn_mfma_f32_16x16x32_bf16(pf, vf, o[hb], 0, 0, 0);
      }
    }
    __syncthreads();
  }

#pragma unroll
  for (int hb = 0; hb < 4; ++hb)
#pragma unroll
    for (int reg = 0; reg < 4; ++reg)
      Op[(size_t)(w * 16 + l4 * 4 + reg) * HSZ + hb * 16 + l15] = o[hb][reg];
  if (l15 == 0) {
#pragma unroll
    for (int reg = 0; reg < 4; ++reg) {
      mp[w * 16 + l4 * 4 + reg] = m_[reg];
      lp[w * 16 + l4 * 4 + reg] = l_[reg];
    }
  }
}

// ---------------------------------------------------------------------------
// Kernel 3b: combine partials -> head (fp32).
// ---------------------------------------------------------------------------
__global__ __launch_bounds__(256) void attn_combine(
    const float* __restrict__ Opart, const float* __restrict__ mpart,
    const float* __restrict__ lpart, float* __restrict__ Hd, int splits) {
  const int qt = blockIdx.x, b = blockIdx.y;
  const int row = threadIdx.x >> 2;
  const int c0 = (threadIdx.x & 3) * 16;
  const int pbase = (b * NQT + qt) * splits;

  float M = -1e30f;
  for (int s = 0; s < splits; ++s)
    M = fmaxf(M, mpart[(size_t)(pbase + s) * QB + row]);

  float L = 0.f;
  float acc[16];
#pragma unroll
  for (int c = 0; c < 16; ++c) acc[c] = 0.f;

  for (int s = 0; s < splits; ++s) {
    const float ms = mpart[(size_t)(pbase + s) * QB + row];
    const float ls = lpart[(size_t)(pbase + s) * QB + row];
    const float w = __expf(ms - M);
    L += w * ls;
    const float* Op = Opart + ((size_t)(pbase + s) * QB + row) * HSZ + c0;
#pragma unroll
    for (int cc = 0; cc < 16; cc += 4) {
      float4 v = *(const float4*)&Op[cc];
      acc[cc + 0] += w * v.x; acc[cc + 1] += w * v.y;
      acc[cc + 2] += w * v.z; acc[cc + 3] += w * v.w;
    }
  }

  const float inv = 1.f / L;
  float* dst = Hd + ((size_t)b * T_SEQ + qt * QB + row) * HSZ + c0;
#pragma unroll
  for (int cc = 0; cc < 16; cc += 4) {
    float4 v = make_float4(acc[cc] * inv, acc[cc + 1] * inv,
                           acc[cc + 2] * inv, acc[cc + 3] * inv);
    *(float4*)&dst[cc] = v;
  }
}

// ---------------------------------------------------------------------------
// Kernel 4: Out = Head @ Wpr + bp   ([8192 x 64] @ [64 x 1024])
// ---------------------------------------------------------------------------
__global__ __launch_bounds__(256) void proj_kernel(const float* __restrict__ Hd,
    const float* __restrict__ Wpr, const float* __restrict__ bp,
    float* __restrict__ Out) {
  __shared__ float Ht[64][68];
  __shared__ float Ws[64][132];
  const int tid = threadIdx.x;
  const int row0 = blockIdx.x * 64;
  const int c0 = blockIdx.y * 128;

  {
    int c = tid & 15, r0 = tid >> 4;
#pragma unroll
    for (int it = 0; it < 4; ++it) {
      int r = r0 + it * 16;
      float4 hv = *(const float4*)&Hd[(size_t)(row0 + r) * HSZ + c * 4];
      Ht[c * 4 + 0][r] = hv.x; Ht[c * 4 + 1][r] = hv.y;
      Ht[c * 4 + 2][r] = hv.z; Ht[c * 4 + 3][r] = hv.w;
    }
  }
  {
    int c = tid & 31, r0 = tid >> 5;
#pragma unroll
    for (int it = 0; it < 8; ++it) {
      int r = r0 + it * 8;
      *(float4*)&Ws[r][c * 4] =
          *(const float4*)&Wpr[(size_t)r * E_DIM + c0 + c * 4];
    }
  }
  __syncthreads();

  const int tx = tid & 15, ty = tid >> 4;
  float acc[4][8] = {};
#pragma unroll
  for (int k = 0; k < 64; ++k) {
    float4 a = *(const float4*)&Ht[k][ty * 4];
    float4 b0 = *(const float4*)&Ws[k][tx * 8];
    float4 b1 = *(const float4*)&Ws[k][tx * 8 + 4];
    float av[4] = {a.x, a.y, a.z, a.w};
    float bv[8] = {b0.x, b0.y, b0.z, b0.w, b1.x, b1.y, b1.z, b1.w};
#pragma unroll
    for (int i = 0; i < 4; ++i)
#pragma unroll
      for (int j = 0; j < 8; ++j) acc[i][j] += av[i] * bv[j];
  }

#pragma unroll
  for (int i = 0; i < 4; ++i) {
    const int row = row0 + ty * 4 + i;
    float4 v0, v1;
    v0.x = acc[i][0] + bp[c0 + tx * 8 + 0];
    v0.y = acc[i][1] + bp[c0 + tx * 8 + 1];
    v0.z = acc[i][2] + bp[c0 + tx * 8 + 2];
    v0.w = acc[i][3] + bp[c0 + tx * 8 + 3];
    v1.x = acc[i][4] + bp[c0 + tx * 8 + 4];
    v1.y = acc[i][5] + bp[c0 + tx * 8 + 5];
    v1.z = acc[i][6] + bp[c0 + tx * 8 + 6];
    v1.w = acc[i][7] + bp[c0 + tx * 8 + 7];
    *(float4*)&Out[(size_t)row * E_DIM + c0 + tx * 8] = v0;
    *(float4*)&Out[(size_t)row * E_DIM + c0 + tx * 8 + 4] = v1;
  }
}

// ---------------------------------------------------------------------------
extern "C" void kernel_launch(void* const* d_in, const int* in_sizes, int n_in,
                              void* d_out, int out_size, void* d_ws,
                              size_t ws_size, hipStream_t stream) {
  (void)in_sizes; (void)n_in; (void)out_size;
  const float* x  = (const float*)d_in[0];
  const float* Wq = (const float*)d_in[1];
  const float* Wk = (const float*)d_in[2];
  const float* Wv = (const float*)d_in[3];
  const float* Wp = (const float*)d_in[4];
  const float* bp = (const float*)d_in[5];
  float* out = (float*)d_out;

  // workspace layout (float units):
  //   Qb16/Kb16/Vt16: bf16, 262144 floats each; Hd fp32 524288;
  //   Wpr 65536; Wt bf16 98304; partials after base.
  float* ws   = (float*)d_ws;
  short* Qb16 = (short*)(ws);
  short* Kb16 = (short*)(ws + 262144);
  short* Vt16 = (short*)(ws + 524288);
  float* Hd   = ws + 786432;
  float* Wpr  = ws + 1310720;
  short* Wt   = (short*)(ws + 1376256);
  const size_t base = 1474560;

  int splits = 8;
  const size_t per_split = (size_t)NBAT * NQT * (QB * HSZ + 2 * QB);
  while (splits > 1 && (base + per_split * splits) * 4 > ws_size) splits >>= 1;

  float* Opart = ws + base;
  float* mpart = Opart + (size_t)NBAT * NQT * splits * QB * HSZ;
  float* lpart = mpart + (size_t)NBAT * NQT * splits * QB;

  wpr_kernel<<<dim3(256), dim3(256), 0, stream>>>(Wp, Wpr);
  wt_kernel<<<dim3(768), dim3(256), 0, stream>>>(Wq, Wk, Wv, Wt);
  qkv_mfma<<<dim3(512), dim3(256), 0, stream>>>(x, Wt, Qb16, Kb16, Vt16);
  attn_part<<<dim3(NQT, splits, NBAT), dim3(256), 0, stream>>>(
      Qb16, Kb16, Vt16, Opart, mpart, lpart, splits);
  attn_combine<<<dim3(NQT, NBAT), dim3(256), 0, stream>>>(
      Opart, mpart, lpart, Hd, splits);
  proj_kernel<<<dim3(128, 8), dim3(256), 0, stream>>>(Hd, Wpr, bp, out);
}

// Round 7
// 150.251 us; speedup vs baseline: 3.2959x; 1.0489x over previous
//
#include <hip/hip_runtime.h>
#include <hip/hip_bf16.h>

#define T_SEQ 2048
#define E_DIM 1024
#define HSZ   64
#define NBAT  4
#define QB    64   // q-rows per attention block
#define NQT   32   // T_SEQ / QB

typedef __attribute__((ext_vector_type(8))) short short8;
typedef __attribute__((ext_vector_type(4))) float f32x4;

__device__ inline short f2bf(float f) {   // fp32 -> bf16 RNE
  union { float f; unsigned u; } v; v.f = f;
  unsigned r = v.u + 0x7FFFu + ((v.u >> 16) & 1u);
  return (short)(r >> 16);
}

// ---------------------------------------------------------------------------
// Kernel 1: folded projection weight, transposed + bf16.
// Wpb[f][j] = bf16( sum_h Wp[h*64+j][f] ),  f in [0,1024), j in [0,64).
// B-fragment-ready ([n][k]) for proj_mfma; 128 KB -> L2-resident.
// ---------------------------------------------------------------------------
__global__ __launch_bounds__(256) void wpr_kernel(const float* __restrict__ Wp,
                                                  short* __restrict__ Wpb) {
  int idx = blockIdx.x * 256 + threadIdx.x;   // 0..65535
  int f = idx & (E_DIM - 1);                  // coalesced read dim
  int j = idx >> 10;                          // 0..63
  float s = 0.f;
#pragma unroll
  for (int h = 0; h < 16; ++h) s += Wp[(size_t)(h * HSZ + j) * E_DIM + f];
  Wpb[(size_t)f * HSZ + j] = f2bf(s);         // transposed scatter (128 KB)
}

// ---------------------------------------------------------------------------
// Kernel 1b: Wt[kt][n][kk] = bf16(Wsel[kt*64+kk][n&63]),  n in [0,192)
// sel = n>>6 picks Wq/Wk/Wv.  B-fragment-ready layout for qkv_mfma.
// ---------------------------------------------------------------------------
__global__ __launch_bounds__(256) void wt_kernel(const float* __restrict__ Wq,
    const float* __restrict__ Wk, const float* __restrict__ Wv,
    short* __restrict__ Wt) {
  int idx = blockIdx.x * 256 + threadIdx.x;   // 0..196607
  int kk = idx & 63;
  int tmp = idx >> 6;
  int kt = tmp / 192;
  int n = tmp - kt * 192;
  const float* W = (n < 64) ? Wq : (n < 128) ? Wk : Wv;
  Wt[idx] = f2bf(W[(size_t)(kt * 64 + kk) * HSZ + (n & 63)]);
}

// ---------------------------------------------------------------------------
// Kernel 2: fused QKV, bf16 MFMA.  C[8192 x 192] = X @ [Wq|Wk|Wv].
// 16-row M-tiles -> 512 blocks.  4 warps x 3 n-blocks (48 cols) each.
// Outputs bf16: Q,K row-major [b*t][hs]; V transposed [b][hd][t].
// ---------------------------------------------------------------------------
__global__ __launch_bounds__(256) void qkv_mfma(const float* __restrict__ X,
    const short* __restrict__ Wt, short* __restrict__ Qo,
    short* __restrict__ Ko, short* __restrict__ Vt) {
  __shared__ short Xs[16 * 64];    // [m][k] swizzled
  __shared__ short Ws[192 * 64];   // [n][k] swizzled

  const int tid = threadIdx.x;
  const int m0 = blockIdx.x * 16;
  const int lane = tid & 63, w = tid >> 6;
  const int l15 = lane & 15, l4 = lane >> 4;

  f32x4 acc[3];
  acc[0] = (f32x4)0.f; acc[1] = (f32x4)0.f; acc[2] = (f32x4)0.f;

  for (int kt = 0; kt < 16; ++kt) {
    const int k0 = kt * 64;
    if (tid < 128) {   // stage X tile: 16 rows x 8 chunks
      int r = tid >> 3, c = tid & 7;
      const float* s = &X[(size_t)(m0 + r) * E_DIM + k0 + c * 8];
      float4 a = *(const float4*)s, d = *(const float4*)(s + 4);
      short8 f;
      f[0] = f2bf(a.x); f[1] = f2bf(a.y); f[2] = f2bf(a.z); f[3] = f2bf(a.w);
      f[4] = f2bf(d.x); f[5] = f2bf(d.y); f[6] = f2bf(d.z); f[7] = f2bf(d.w);
      *(short8*)&Xs[r * 64 + ((c ^ (r & 7)) * 8)] = f;
    }
    {   // stage W panel: 192 rows x 8 chunks = 1536, contiguous source
      const short* wsrc = Wt + (size_t)kt * 12288;
#pragma unroll
      for (int i = 0; i < 6; ++i) {
        int ci = tid + i * 256;
        int r = ci >> 3, c = ci & 7;
        short8 f = *(const short8*)&wsrc[ci * 8];
        *(short8*)&Ws[r * 64 + ((c ^ (r & 7)) * 8)] = f;
      }
    }
    __syncthreads();
#pragma unroll
    for (int ks = 0; ks < 2; ++ks) {
      short8 af = *(short8*)&Xs[l15 * 64 + (((ks * 4 + l4) ^ (l15 & 7)) * 8)];
#pragma unroll
      for (int i = 0; i < 3; ++i) {
        int n = (w * 3 + i) * 16 + l15;
        short8 bf = *(short8*)&Ws[n * 64 + (((ks * 4 + l4) ^ (n & 7)) * 8)];
        acc[i] = __builtin_amdgcn_mfma_f32_16x16x32_bf16(af, bf, acc[i], 0, 0, 0);
      }
    }
    __syncthreads();
  }

  // epilogue: C/D layout col=l15, row=l4*4+reg
  const int b = m0 >> 11, t = m0 & 2047;
#pragma unroll
  for (int i = 0; i < 3; ++i) {
    const int nb = w * 3 + i;             // 0..11
    const int col = (nb & 3) * 16 + l15;  // 0..63 within Q/K/V
    const int sel = nb >> 2;
#pragma unroll
    for (int reg = 0; reg < 4; ++reg) {
      const int row = l4 * 4 + reg;
      short v = f2bf(acc[i][reg]);
      if (sel == 0)      Qo[(size_t)(m0 + row) * HSZ + col] = v;
      else if (sel == 1) Ko[(size_t)(m0 + row) * HSZ + col] = v;
      else               Vt[((size_t)b * HSZ + col) * T_SEQ + t + row] = v;
    }
  }
}

// ---------------------------------------------------------------------------
// Kernel 3a: split-K causal flash attention partials, bf16 MFMA.
// ---------------------------------------------------------------------------
__global__ __launch_bounds__(256) void attn_part(const short* __restrict__ Q,
    const short* __restrict__ K, const short* __restrict__ Vt,
    float* __restrict__ Opart, float* __restrict__ mpart,
    float* __restrict__ lpart, int splits) {
  const int qt = blockIdx.x;
  const int sp = blockIdx.y;
  const int b  = blockIdx.z;
  const int ntile = qt + 1;
  const int t0 = (sp * ntile) / splits;
  const int t1 = ((sp + 1) * ntile) / splits;
  const int q0 = qt * QB;
  const int pidx = (b * NQT + qt) * splits + sp;
  float* Op = Opart + (size_t)pidx * QB * HSZ;
  float* mp = mpart + (size_t)pidx * QB;
  float* lp = lpart + (size_t)pidx * QB;
  const int tid = threadIdx.x;

  if (t0 >= t1) {
    if (tid < QB) { mp[tid] = -1e30f; lp[tid] = 0.f; }
    return;
  }

  const short* Qb  = Q  + (size_t)b * T_SEQ * HSZ;
  const short* Kb  = K  + (size_t)b * T_SEQ * HSZ;
  const short* Vtb = Vt + (size_t)b * HSZ * T_SEQ;

  __shared__ short Ks[64 * 64];
  __shared__ short Vs[64 * 64];
  __shared__ short Ps[4][16 * 64];

  const int lane = tid & 63;
  const int w    = tid >> 6;
  const int l15  = lane & 15;
  const int l4   = lane >> 4;

  short8 qf[2];
#pragma unroll
  for (int ks = 0; ks < 2; ++ks)
    qf[ks] = *(const short8*)&Qb[(size_t)(q0 + w * 16 + l15) * HSZ + ks * 32 + l4 * 8];

  f32x4 o[4];
  float m_[4], l_[4];
#pragma unroll
  for (int i = 0; i < 4; ++i) { o[i] = (f32x4)0.f; m_[i] = -1e30f; l_[i] = 0.f; }

  for (int kt = t0; kt < t1; ++kt) {
    const int kv0 = kt * 64;
#pragma unroll
    for (int ci = tid; ci < 512; ci += 256) {   // K: [kv][hd]
      int r = ci >> 3, c = ci & 7;
      short8 f = *(const short8*)&Kb[(size_t)(kv0 + r) * HSZ + c * 8];
      *(short8*)&Ks[r * 64 + ((c ^ (r & 7)) * 8)] = f;
    }
#pragma unroll
    for (int ci = tid; ci < 512; ci += 256) {   // V^T: [hd][kv]
      int r = ci >> 3, c = ci & 7;
      short8 f = *(const short8*)&Vtb[(size_t)r * T_SEQ + kv0 + c * 8];
      *(short8*)&Vs[r * 64 + ((c ^ (r & 7)) * 8)] = f;
    }
    __syncthreads();

    f32x4 sacc[4];
#pragma unroll
    for (int nb = 0; nb < 4; ++nb) sacc[nb] = (f32x4)0.f;
#pragma unroll
    for (int nb = 0; nb < 4; ++nb) {
      const int krow = nb * 16 + l15;
#pragma unroll
      for (int ks = 0; ks < 2; ++ks) {
        short8 kf = *(short8*)&Ks[krow * 64 + (((ks * 4 + l4) ^ (krow & 7)) * 8)];
        sacc[nb] = __builtin_amdgcn_mfma_f32_16x16x32_bf16(qf[ks], kf, sacc[nb],
                                                           0, 0, 0);
      }
    }

    const bool diag = (kt == qt);
#pragma unroll
    for (int reg = 0; reg < 4; ++reg) {
      const int grow = q0 + w * 16 + l4 * 4 + reg;
      float sv[4];
      float rmax = -1e30f;
#pragma unroll
      for (int nb = 0; nb < 4; ++nb) {
        sv[nb] = sacc[nb][reg] * 0.125f;
        if (diag && (kv0 + nb * 16 + l15 > grow)) sv[nb] = -1e30f;
        rmax = fmaxf(rmax, sv[nb]);
      }
#pragma unroll
      for (int d = 1; d < 16; d <<= 1) rmax = fmaxf(rmax, __shfl_xor(rmax, d));
      const float mn = fmaxf(m_[reg], rmax);
      const float sc = __expf(m_[reg] - mn);
      float rsum = 0.f;
#pragma unroll
      for (int nb = 0; nb < 4; ++nb) {
        sv[nb] = __expf(sv[nb] - mn);
        rsum += sv[nb];
      }
#pragma unroll
      for (int d = 1; d < 16; d <<= 1) rsum += __shfl_xor(rsum, d);
      l_[reg] = l_[reg] * sc + rsum;
      m_[reg] = mn;
#pragma unroll
      for (int hb = 0; hb < 4; ++hb) o[hb][reg] *= sc;
      const int prow = l4 * 4 + reg;
#pragma unroll
      for (int nb = 0; nb < 4; ++nb) {
        const int col = nb * 16 + l15;
        Ps[w][prow * 64 + (((col >> 3) ^ (prow & 7)) * 8) + (col & 7)] =
            f2bf(sv[nb]);
      }
    }

#pragma unroll
    for (int ks = 0; ks < 2; ++ks) {
      const int prow = l15;
      short8 pf = *(short8*)&Ps[w][prow * 64 + (((ks * 4 + l4) ^ (prow & 7)) * 8)];
#pragma unroll
      for (int hb = 0; hb < 4; ++hb) {
        const int vrow = hb * 16 + l15;
        short8 vf = *(short8*)&Vs[vrow * 64 + (((ks * 4 + l4) ^ (vrow & 7)) * 8)];
        o[hb] = __builtin_amdgcn_mfma_f32_16x16x32_bf16(pf, vf, o[hb], 0, 0, 0);
      }
    }
    __syncthreads();
  }

#pragma unroll
  for (int hb = 0; hb < 4; ++hb)
#pragma unroll
    for (int reg = 0; reg < 4; ++reg)
      Op[(size_t)(w * 16 + l4 * 4 + reg) * HSZ + hb * 16 + l15] = o[hb][reg];
  if (l15 == 0) {
#pragma unroll
    for (int reg = 0; reg < 4; ++reg) {
      mp[w * 16 + l4 * 4 + reg] = m_[reg];
      lp[w * 16 + l4 * 4 + reg] = l_[reg];
    }
  }
}

// ---------------------------------------------------------------------------
// Kernel 3b: combine partials -> head, emitted bf16 (A-frag-ready for proj).
// ---------------------------------------------------------------------------
__global__ __launch_bounds__(256) void attn_combine(
    const float* __restrict__ Opart, const float* __restrict__ mpart,
    const float* __restrict__ lpart, short* __restrict__ Hd16, int splits) {
  const int qt = blockIdx.x, b = blockIdx.y;
  const int row = threadIdx.x >> 2;
  const int c0 = (threadIdx.x & 3) * 16;
  const int pbase = (b * NQT + qt) * splits;

  float M = -1e30f;
  for (int s = 0; s < splits; ++s)
    M = fmaxf(M, mpart[(size_t)(pbase + s) * QB + row]);

  float L = 0.f;
  float acc[16];
#pragma unroll
  for (int c = 0; c < 16; ++c) acc[c] = 0.f;

  for (int s = 0; s < splits; ++s) {
    const float ms = mpart[(size_t)(pbase + s) * QB + row];
    const float ls = lpart[(size_t)(pbase + s) * QB + row];
    const float w = __expf(ms - M);
    L += w * ls;
    const float* Op = Opart + ((size_t)(pbase + s) * QB + row) * HSZ + c0;
#pragma unroll
    for (int cc = 0; cc < 16; cc += 4) {
      float4 v = *(const float4*)&Op[cc];
      acc[cc + 0] += w * v.x; acc[cc + 1] += w * v.y;
      acc[cc + 2] += w * v.z; acc[cc + 3] += w * v.w;
    }
  }

  const float inv = 1.f / L;
  short* dst = Hd16 + ((size_t)b * T_SEQ + qt * QB + row) * HSZ + c0;
  short8 v0, v1;
#pragma unroll
  for (int cc = 0; cc < 8; ++cc) {
    v0[cc] = f2bf(acc[cc] * inv);
    v1[cc] = f2bf(acc[8 + cc] * inv);
  }
  *(short8*)dst = v0;
  *(short8*)(dst + 8) = v1;
}

// ---------------------------------------------------------------------------
// Kernel 4: Out = Head @ Wpr + bp via bf16 MFMA, ZERO LDS.
// K=64 -> 2 chained mfma per 16x16 tile; A/B read directly from global (L2).
// grid (128 M-blocks, 8 N-chunks) x 256 thr; warp w: rows bx*64+w*16..+15.
// ---------------------------------------------------------------------------
__global__ __launch_bounds__(256) void proj_mfma(const short* __restrict__ Hd16,
    const short* __restrict__ Wpb, const float* __restrict__ bp,
    float* __restrict__ Out) {
  const int tid = threadIdx.x;
  const int lane = tid & 63, w = tid >> 6;
  const int l15 = lane & 15, l4 = lane >> 4;
  const int m0 = blockIdx.x * 64 + w * 16;
  const int n0 = blockIdx.y * 128;

  const short* asrc = &Hd16[(size_t)(m0 + l15) * HSZ + l4 * 8];
  short8 af0 = *(const short8*)asrc;
  short8 af1 = *(const short8*)(asrc + 32);

#pragma unroll
  for (int nb = 0; nb < 8; ++nb) {
    const int n = n0 + nb * 16 + l15;
    const short* bsrc = &Wpb[(size_t)n * HSZ + l4 * 8];
    short8 b0 = *(const short8*)bsrc;
    short8 b1 = *(const short8*)(bsrc + 32);
    f32x4 acc = (f32x4)0.f;
    acc = __builtin_amdgcn_mfma_f32_16x16x32_bf16(af0, b0, acc, 0, 0, 0);
    acc = __builtin_amdgcn_mfma_f32_16x16x32_bf16(af1, b1, acc, 0, 0, 0);
    const float bpv = bp[n];
#pragma unroll
    for (int reg = 0; reg < 4; ++reg)
      Out[(size_t)(m0 + l4 * 4 + reg) * E_DIM + n] = acc[reg] + bpv;
  }
}

// ---------------------------------------------------------------------------
extern "C" void kernel_launch(void* const* d_in, const int* in_sizes, int n_in,
                              void* d_out, int out_size, void* d_ws,
                              size_t ws_size, hipStream_t stream) {
  (void)in_sizes; (void)n_in; (void)out_size;
  const float* x  = (const float*)d_in[0];
  const float* Wq = (const float*)d_in[1];
  const float* Wk = (const float*)d_in[2];
  const float* Wv = (const float*)d_in[3];
  const float* Wp = (const float*)d_in[4];
  const float* bp = (const float*)d_in[5];
  float* out = (float*)d_out;

  // workspace layout (float units):
  //   Qb16/Kb16/Vt16/Hd16: bf16 [4*2048*64] = 262144 floats each;
  //   Wpb bf16 32768; Wt bf16 98304; partials after base.
  float* ws   = (float*)d_ws;
  short* Qb16 = (short*)(ws);
  short* Kb16 = (short*)(ws + 262144);
  short* Vt16 = (short*)(ws + 524288);
  short* Hd16 = (short*)(ws + 786432);
  short* Wpb  = (short*)(ws + 1048576);
  short* Wt   = (short*)(ws + 1081344);
  const size_t base = 1179648;

  int splits = 8;
  const size_t per_split = (size_t)NBAT * NQT * (QB * HSZ + 2 * QB);
  while (splits > 1 && (base + per_split * splits) * 4 > ws_size) splits >>= 1;

  float* Opart = ws + base;
  float* mpart = Opart + (size_t)NBAT * NQT * splits * QB * HSZ;
  float* lpart = mpart + (size_t)NBAT * NQT * splits * QB;

  wpr_kernel<<<dim3(256), dim3(256), 0, stream>>>(Wp, Wpb);
  wt_kernel<<<dim3(768), dim3(256), 0, stream>>>(Wq, Wk, Wv, Wt);
  qkv_mfma<<<dim3(512), dim3(256), 0, stream>>>(x, Wt, Qb16, Kb16, Vt16);
  attn_part<<<dim3(NQT, splits, NBAT), dim3(256), 0, stream>>>(
      Qb16, Kb16, Vt16, Opart, mpart, lpart, splits);
  attn_combine<<<dim3(NQT, NBAT), dim3(256), 0, stream>>>(
      Opart, mpart, lpart, Hd16, splits);
  proj_mfma<<<dim3(128, 8), dim3(256), 0, stream>>>(Hd16, Wpb, bp, out);
}

// Round 8
// 149.789 us; speedup vs baseline: 3.3060x; 1.0031x over previous
//
#include <hip/hip_runtime.h>
#include <hip/hip_bf16.h>

#define T_SEQ 2048
#define E_DIM 1024
#define HSZ   64
#define NBAT  4
#define QB    64   // q-rows per attention block
#define NQT   32   // T_SEQ / QB

typedef __attribute__((ext_vector_type(8))) short short8;
typedef __attribute__((ext_vector_type(4))) float f32x4;

__device__ inline short f2bf(float f) {   // fp32 -> bf16 RNE
  union { float f; unsigned u; } v; v.f = f;
  unsigned r = v.u + 0x7FFFu + ((v.u >> 16) & 1u);
  return (short)(r >> 16);
}

// ---------------------------------------------------------------------------
// Kernel 1 (fused prep):
//   idx < 65536 : Wpb[f][j] = bf16(sum_h Wp[h*64+j][f])   (proj B-frags)
//   else        : Wt[kt][n][kk] = bf16(Wsel[kt*64+kk][n&63])  (qkv B-frags)
// ---------------------------------------------------------------------------
__global__ __launch_bounds__(256) void prep_kernel(const float* __restrict__ Wp,
    const float* __restrict__ Wq, const float* __restrict__ Wk,
    const float* __restrict__ Wv, short* __restrict__ Wpb,
    short* __restrict__ Wt) {
  int idx = blockIdx.x * 256 + threadIdx.x;   // 0..262143
  if (idx < 65536) {
    int f = idx & (E_DIM - 1);
    int j = idx >> 10;
    float s = 0.f;
#pragma unroll
    for (int h = 0; h < 16; ++h) s += Wp[(size_t)(h * HSZ + j) * E_DIM + f];
    Wpb[(size_t)f * HSZ + j] = f2bf(s);
  } else {
    int id2 = idx - 65536;                    // 0..196607
    int kk = id2 & 63;
    int tmp = id2 >> 6;
    int kt = tmp / 192;
    int n = tmp - kt * 192;
    const float* W = (n < 64) ? Wq : (n < 128) ? Wk : Wv;
    Wt[id2] = f2bf(W[(size_t)(kt * 64 + kk) * HSZ + (n & 63)]);
  }
}

// ---------------------------------------------------------------------------
// Kernel 2: fused QKV, bf16 MFMA.  C[8192 x 192] = X @ [Wq|Wk|Wv].
// Outputs bf16: Q,K row-major [b*t][hs]; V transposed [b][hd][t].
// ---------------------------------------------------------------------------
__global__ __launch_bounds__(256) void qkv_mfma(const float* __restrict__ X,
    const short* __restrict__ Wt, short* __restrict__ Qo,
    short* __restrict__ Ko, short* __restrict__ Vt) {
  __shared__ short Xs[16 * 64];    // [m][k] swizzled
  __shared__ short Ws[192 * 64];   // [n][k] swizzled

  const int tid = threadIdx.x;
  const int m0 = blockIdx.x * 16;
  const int lane = tid & 63, w = tid >> 6;
  const int l15 = lane & 15, l4 = lane >> 4;

  f32x4 acc[3];
  acc[0] = (f32x4)0.f; acc[1] = (f32x4)0.f; acc[2] = (f32x4)0.f;

  for (int kt = 0; kt < 16; ++kt) {
    const int k0 = kt * 64;
    if (tid < 128) {   // stage X tile: 16 rows x 8 chunks
      int r = tid >> 3, c = tid & 7;
      const float* s = &X[(size_t)(m0 + r) * E_DIM + k0 + c * 8];
      float4 a = *(const float4*)s, d = *(const float4*)(s + 4);
      short8 f;
      f[0] = f2bf(a.x); f[1] = f2bf(a.y); f[2] = f2bf(a.z); f[3] = f2bf(a.w);
      f[4] = f2bf(d.x); f[5] = f2bf(d.y); f[6] = f2bf(d.z); f[7] = f2bf(d.w);
      *(short8*)&Xs[r * 64 + ((c ^ (r & 7)) * 8)] = f;
    }
    {   // stage W panel: 192 rows x 8 chunks = 1536, contiguous source
      const short* wsrc = Wt + (size_t)kt * 12288;
#pragma unroll
      for (int i = 0; i < 6; ++i) {
        int ci = tid + i * 256;
        int r = ci >> 3, c = ci & 7;
        short8 f = *(const short8*)&wsrc[ci * 8];
        *(short8*)&Ws[r * 64 + ((c ^ (r & 7)) * 8)] = f;
      }
    }
    __syncthreads();
#pragma unroll
    for (int ks = 0; ks < 2; ++ks) {
      short8 af = *(short8*)&Xs[l15 * 64 + (((ks * 4 + l4) ^ (l15 & 7)) * 8)];
#pragma unroll
      for (int i = 0; i < 3; ++i) {
        int n = (w * 3 + i) * 16 + l15;
        short8 bf = *(short8*)&Ws[n * 64 + (((ks * 4 + l4) ^ (n & 7)) * 8)];
        acc[i] = __builtin_amdgcn_mfma_f32_16x16x32_bf16(af, bf, acc[i], 0, 0, 0);
      }
    }
    __syncthreads();
  }

  const int b = m0 >> 11, t = m0 & 2047;
#pragma unroll
  for (int i = 0; i < 3; ++i) {
    const int nb = w * 3 + i;
    const int col = (nb & 3) * 16 + l15;
    const int sel = nb >> 2;
#pragma unroll
    for (int reg = 0; reg < 4; ++reg) {
      const int row = l4 * 4 + reg;
      short v = f2bf(acc[i][reg]);
      if (sel == 0)      Qo[(size_t)(m0 + row) * HSZ + col] = v;
      else if (sel == 1) Ko[(size_t)(m0 + row) * HSZ + col] = v;
      else               Vt[((size_t)b * HSZ + col) * T_SEQ + t + row] = v;
    }
  }
}

// ---------------------------------------------------------------------------
// Kernel 3: split-K causal flash attention partials, bf16 MFMA.
// T14 async-stage: next tile's K/V loaded to regs BEFORE compute, written to
// the other LDS buffer after; ONE barrier per tile (Ps is per-warp).
// ---------------------------------------------------------------------------
__global__ __launch_bounds__(256) void attn_part(const short* __restrict__ Q,
    const short* __restrict__ K, const short* __restrict__ Vt,
    float* __restrict__ Opart, float* __restrict__ mpart,
    float* __restrict__ lpart, int splits) {
  const int qt = blockIdx.x;
  const int sp = blockIdx.y;
  const int b  = blockIdx.z;
  const int ntile = qt + 1;
  const int t0 = (sp * ntile) / splits;
  const int t1 = ((sp + 1) * ntile) / splits;
  const int q0 = qt * QB;
  const int pidx = (b * NQT + qt) * splits + sp;
  float* Op = Opart + (size_t)pidx * QB * HSZ;
  float* mp = mpart + (size_t)pidx * QB;
  float* lp = lpart + (size_t)pidx * QB;
  const int tid = threadIdx.x;

  if (t0 >= t1) {
    if (tid < QB) { mp[tid] = -1e30f; lp[tid] = 0.f; }
    return;
  }

  const short* Qb  = Q  + (size_t)b * T_SEQ * HSZ;
  const short* Kb  = K  + (size_t)b * T_SEQ * HSZ;
  const short* Vtb = Vt + (size_t)b * HSZ * T_SEQ;

  __shared__ short Ks[2][64 * 64];
  __shared__ short Vs[2][64 * 64];
  __shared__ short Ps[4][16 * 64];

  const int lane = tid & 63;
  const int w    = tid >> 6;
  const int l15  = lane & 15;
  const int l4   = lane >> 4;

  // staging coords: two 16B chunks per thread (512 chunks total)
  const int r0s = tid >> 3,          c0s = tid & 7;
  const int r1s = (tid + 256) >> 3,  c1s = tid & 7;   // (tid+256)&7 == tid&7

  short8 kr0, kr1, vr0, vr1;
#define LOADT(kt_) do { \
    const int kv0_ = (kt_) * 64; \
    kr0 = *(const short8*)&Kb[(size_t)(kv0_ + r0s) * HSZ + c0s * 8]; \
    kr1 = *(const short8*)&Kb[(size_t)(kv0_ + r1s) * HSZ + c1s * 8]; \
    vr0 = *(const short8*)&Vtb[(size_t)r0s * T_SEQ + kv0_ + c0s * 8]; \
    vr1 = *(const short8*)&Vtb[(size_t)r1s * T_SEQ + kv0_ + c1s * 8]; \
  } while (0)
#define WRITET(buf_) do { \
    *(short8*)&Ks[buf_][r0s * 64 + ((c0s ^ (r0s & 7)) * 8)] = kr0; \
    *(short8*)&Ks[buf_][r1s * 64 + ((c1s ^ (r1s & 7)) * 8)] = kr1; \
    *(short8*)&Vs[buf_][r0s * 64 + ((c0s ^ (r0s & 7)) * 8)] = vr0; \
    *(short8*)&Vs[buf_][r1s * 64 + ((c1s ^ (r1s & 7)) * 8)] = vr1; \
  } while (0)

  short8 qf[2];
#pragma unroll
  for (int ks = 0; ks < 2; ++ks)
    qf[ks] = *(const short8*)&Qb[(size_t)(q0 + w * 16 + l15) * HSZ + ks * 32 + l4 * 8];

  f32x4 o[4];
  float m_[4], l_[4];
#pragma unroll
  for (int i = 0; i < 4; ++i) { o[i] = (f32x4)0.f; m_[i] = -1e30f; l_[i] = 0.f; }

  LOADT(t0);
  WRITET(0);
  __syncthreads();
  int cur = 0;

  for (int kt = t0; kt < t1; ++kt) {
    const int kv0 = kt * 64;
    const bool more = (kt + 1 < t1);
    if (more) LOADT(kt + 1);          // global->reg, in flight under compute

    const short* Kc = Ks[cur];
    const short* Vc = Vs[cur];

    f32x4 sacc[4];
#pragma unroll
    for (int nb = 0; nb < 4; ++nb) sacc[nb] = (f32x4)0.f;
#pragma unroll
    for (int nb = 0; nb < 4; ++nb) {
      const int krow = nb * 16 + l15;
#pragma unroll
      for (int ks = 0; ks < 2; ++ks) {
        short8 kf = *(const short8*)&Kc[krow * 64 + (((ks * 4 + l4) ^ (krow & 7)) * 8)];
        sacc[nb] = __builtin_amdgcn_mfma_f32_16x16x32_bf16(qf[ks], kf, sacc[nb],
                                                           0, 0, 0);
      }
    }

    const bool diag = (kt == qt);
#pragma unroll
    for (int reg = 0; reg < 4; ++reg) {
      const int grow = q0 + w * 16 + l4 * 4 + reg;
      float sv[4];
      float rmax = -1e30f;
#pragma unroll
      for (int nb = 0; nb < 4; ++nb) {
        sv[nb] = sacc[nb][reg] * 0.125f;
        if (diag && (kv0 + nb * 16 + l15 > grow)) sv[nb] = -1e30f;
        rmax = fmaxf(rmax, sv[nb]);
      }
#pragma unroll
      for (int d = 1; d < 16; d <<= 1) rmax = fmaxf(rmax, __shfl_xor(rmax, d));
      const float mn = fmaxf(m_[reg], rmax);
      const float sc = __expf(m_[reg] - mn);
      float rsum = 0.f;
#pragma unroll
      for (int nb = 0; nb < 4; ++nb) {
        sv[nb] = __expf(sv[nb] - mn);
        rsum += sv[nb];
      }
#pragma unroll
      for (int d = 1; d < 16; d <<= 1) rsum += __shfl_xor(rsum, d);
      l_[reg] = l_[reg] * sc + rsum;
      m_[reg] = mn;
#pragma unroll
      for (int hb = 0; hb < 4; ++hb) o[hb][reg] *= sc;
      const int prow = l4 * 4 + reg;
#pragma unroll
      for (int nb = 0; nb < 4; ++nb) {
        const int col = nb * 16 + l15;
        Ps[w][prow * 64 + (((col >> 3) ^ (prow & 7)) * 8) + (col & 7)] =
            f2bf(sv[nb]);
      }
    }

#pragma unroll
    for (int ks = 0; ks < 2; ++ks) {
      const int prow = l15;
      short8 pf = *(short8*)&Ps[w][prow * 64 + (((ks * 4 + l4) ^ (prow & 7)) * 8)];
#pragma unroll
      for (int hb = 0; hb < 4; ++hb) {
        const int vrow = hb * 16 + l15;
        short8 vf = *(const short8*)&Vc[vrow * 64 + (((ks * 4 + l4) ^ (vrow & 7)) * 8)];
        o[hb] = __builtin_amdgcn_mfma_f32_16x16x32_bf16(pf, vf, o[hb], 0, 0, 0);
      }
    }

    if (more) {
      WRITET(cur ^ 1);      // waits vmcnt here, not at compute
      __syncthreads();
      cur ^= 1;
    }
  }
#undef LOADT
#undef WRITET

#pragma unroll
  for (int hb = 0; hb < 4; ++hb)
#pragma unroll
    for (int reg = 0; reg < 4; ++reg)
      Op[(size_t)(w * 16 + l4 * 4 + reg) * HSZ + hb * 16 + l15] = o[hb][reg];
  if (l15 == 0) {
#pragma unroll
    for (int reg = 0; reg < 4; ++reg) {
      mp[w * 16 + l4 * 4 + reg] = m_[reg];
      lp[w * 16 + l4 * 4 + reg] = l_[reg];
    }
  }
}

// ---------------------------------------------------------------------------
// Kernel 4: fused combine + projection.  grid (128, 4), 256 threads.
// Block bx = b*32+qt owns q-tile rows bx*64..+63; combines partials straight
// into MFMA A-fragments in registers, then Out = A @ Wpb + bp over 256 cols.
// ---------------------------------------------------------------------------
__global__ __launch_bounds__(256) void proj_fused(
    const float* __restrict__ Opart, const float* __restrict__ mpart,
    const float* __restrict__ lpart, const short* __restrict__ Wpb,
    const float* __restrict__ bp, float* __restrict__ Out, int splits) {
  const int bx = blockIdx.x;              // 0..127
  const int n0 = blockIdx.y * 256;        // 4 n-chunks
  const int tid = threadIdx.x;
  const int lane = tid & 63, w = tid >> 6;
  const int l15 = lane & 15, l4 = lane >> 4;
  const int r = w * 16 + l15;             // row within q-tile
  const int pbase = bx * splits;

  // ---- combine partials -> A-fragments (row=l15, k=l4*8+j / +32) ----
  float M = -1e30f;
  for (int s = 0; s < splits; ++s)
    M = fmaxf(M, mpart[(size_t)(pbase + s) * QB + r]);
  float L = 0.f;
  float a0[8], a1[8];
#pragma unroll
  for (int j = 0; j < 8; ++j) { a0[j] = 0.f; a1[j] = 0.f; }
  for (int s = 0; s < splits; ++s) {
    const float ms = mpart[(size_t)(pbase + s) * QB + r];
    const float ls = lpart[(size_t)(pbase + s) * QB + r];
    const float wgt = __expf(ms - M);
    L += wgt * ls;
    const float* Opr = Opart + ((size_t)(pbase + s) * QB + r) * HSZ;
    float4 p0 = *(const float4*)&Opr[l4 * 8];
    float4 p1 = *(const float4*)&Opr[l4 * 8 + 4];
    float4 p2 = *(const float4*)&Opr[32 + l4 * 8];
    float4 p3 = *(const float4*)&Opr[32 + l4 * 8 + 4];
    a0[0] += wgt * p0.x; a0[1] += wgt * p0.y; a0[2] += wgt * p0.z; a0[3] += wgt * p0.w;
    a0[4] += wgt * p1.x; a0[5] += wgt * p1.y; a0[6] += wgt * p1.z; a0[7] += wgt * p1.w;
    a1[0] += wgt * p2.x; a1[1] += wgt * p2.y; a1[2] += wgt * p2.z; a1[3] += wgt * p2.w;
    a1[4] += wgt * p3.x; a1[5] += wgt * p3.y; a1[6] += wgt * p3.z; a1[7] += wgt * p3.w;
  }
  const float inv = 1.f / L;
  short8 af0, af1;
#pragma unroll
  for (int j = 0; j < 8; ++j) {
    af0[j] = f2bf(a0[j] * inv);
    af1[j] = f2bf(a1[j] * inv);
  }

  // ---- GEMM: 16 n-tiles x (2 loads + 2 MFMA + strided stores) ----
  const int mbase = bx * 64 + w * 16 + l4 * 4;
#pragma unroll 4
  for (int nb = 0; nb < 16; ++nb) {
    const int n = n0 + nb * 16 + l15;
    const short* bsrc = &Wpb[(size_t)n * HSZ + l4 * 8];
    short8 b0 = *(const short8*)bsrc;
    short8 b1 = *(const short8*)(bsrc + 32);
    f32x4 acc = (f32x4)0.f;
    acc = __builtin_amdgcn_mfma_f32_16x16x32_bf16(af0, b0, acc, 0, 0, 0);
    acc = __builtin_amdgcn_mfma_f32_16x16x32_bf16(af1, b1, acc, 0, 0, 0);
    const float bpv = bp[n];
#pragma unroll
    for (int reg = 0; reg < 4; ++reg)
      Out[(size_t)(mbase + reg) * E_DIM + n] = acc[reg] + bpv;
  }
}

// ---------------------------------------------------------------------------
extern "C" void kernel_launch(void* const* d_in, const int* in_sizes, int n_in,
                              void* d_out, int out_size, void* d_ws,
                              size_t ws_size, hipStream_t stream) {
  (void)in_sizes; (void)n_in; (void)out_size;
  const float* x  = (const float*)d_in[0];
  const float* Wq = (const float*)d_in[1];
  const float* Wk = (const float*)d_in[2];
  const float* Wv = (const float*)d_in[3];
  const float* Wp = (const float*)d_in[4];
  const float* bp = (const float*)d_in[5];
  float* out = (float*)d_out;

  // workspace layout (float units):
  //   Qb16/Kb16/Vt16 bf16 262144 each; Wpb bf16 32768; Wt bf16 98304.
  float* ws   = (float*)d_ws;
  short* Qb16 = (short*)(ws);
  short* Kb16 = (short*)(ws + 262144);
  short* Vt16 = (short*)(ws + 524288);
  short* Wpb  = (short*)(ws + 786432);
  short* Wt   = (short*)(ws + 819200);
  const size_t base = 917504;

  int splits = 8;
  const size_t per_split = (size_t)NBAT * NQT * (QB * HSZ + 2 * QB);
  while (splits > 1 && (base + per_split * splits) * 4 > ws_size) splits >>= 1;

  float* Opart = ws + base;
  float* mpart = Opart + (size_t)NBAT * NQT * splits * QB * HSZ;
  float* lpart = mpart + (size_t)NBAT * NQT * splits * QB;

  prep_kernel<<<dim3(1024), dim3(256), 0, stream>>>(Wp, Wq, Wk, Wv, Wpb, Wt);
  qkv_mfma<<<dim3(512), dim3(256), 0, stream>>>(x, Wt, Qb16, Kb16, Vt16);
  attn_part<<<dim3(NQT, splits, NBAT), dim3(256), 0, stream>>>(
      Qb16, Kb16, Vt16, Opart, mpart, lpart, splits);
  proj_fused<<<dim3(128, 4), dim3(256), 0, stream>>>(
      Opart, mpart, lpart, Wpb, bp, out, splits);
}